// Round 7
// baseline (625.336 us; speedup 1.0000x reference)
//
#include <hip/hip_runtime.h>
#include <math.h>

typedef unsigned int   uint32;
typedef unsigned short ushort16;
typedef __attribute__((ext_vector_type(8))) short  short8;   // 8 bf16 (MFMA A/B frag)
typedef __attribute__((ext_vector_type(4))) float  floatx4;  // MFMA C/D frag

// Problem dims
#define Bb   512
#define QLn  128
#define ALn  512
#define En   300
#define Fn   400
#define OW   416      // packed output width: 400 real + 16 zero (832 B = 13*64)
#define EPAD 320      // e padded 300 -> 320 per shift
#define NV   50001
#define ECROWS 50176  // 196*256 padded vocab rows
#define ECSTRIDE 2560 // 1280 cols * 2B (3*416 used + 32 pad)

typedef const __attribute__((address_space(1))) unsigned int guint_t;
typedef __attribute__((address_space(3))) unsigned int luint_t;
#define GLDS16(g, l) __builtin_amdgcn_global_load_lds((guint_t*)(g), (luint_t*)(l), 16, 0, 0)

static __device__ __forceinline__ float bf_lo(uint32 u) { return __uint_as_float(u << 16); }
static __device__ __forceinline__ float bf_hi(uint32 u) { return __uint_as_float(u & 0xffff0000u); }
static __device__ __forceinline__ ushort16 f2bf(float f) {
    uint32 u = __float_as_uint(f);
    uint32 r = (u + 0x7fffu + ((u >> 16) & 1u)) >> 16;   // RNE
    return (ushort16)r;
}
static __device__ __forceinline__ uint32 pack2(float a, float b) {
    return (uint32)f2bf(a) | ((uint32)f2bf(b) << 16);
}

// ---------------------------------------------------------------------------
// embcvt: embbf[v][0..320) = bf16(emb[v][0..300)), e>=300 zero.
// ---------------------------------------------------------------------------
__global__ __launch_bounds__(128) void embcvt_kernel(
        const float* __restrict__ emb, char* __restrict__ embbf)
{
    const int r = blockIdx.x, j = threadIdx.x;
    const float* er = emb + (size_t)r * En;
    uint32* orow = (uint32*)(embbf + (size_t)r * 640);
    for (int d = j; d < 160; d += 128) {
        uint32 v = 0;
        if (d < 150) {
            float2 f2v = *(const float2*)(er + 2 * d);
            v = pack2(f2v.x, f2v.y);
        }
        orow[d] = v;
    }
}

// ---------------------------------------------------------------------------
// prep_wt: Wt2[f][p] = W[f][e*3+kk] (p = kk*320+e), bf16, zero pad; bias2.
// Rows f in [400,512) are fully zero (used as zero-rows by ec_gemm pad).
// ---------------------------------------------------------------------------
__global__ __launch_bounds__(256) void prep_wt(
        const float* __restrict__ W, const float* __restrict__ cb,
        ushort16* __restrict__ Wt2, float* __restrict__ bias2)
{
    const int f = blockIdx.x, t = threadIdx.x;
    for (int p2 = t; p2 < 480; p2 += 256) {
        int p = 2 * p2;
        float v0 = 0.f, v1 = 0.f;
        if (f < Fn) {
            int kk = p / EPAD, e = p - kk * EPAD;
            if (e < En)     v0 = W[(size_t)f * 900 + e * 3 + kk];
            if (e + 1 < En) v1 = W[(size_t)f * 900 + (e + 1) * 3 + kk];
        }
        *(uint32*)&Wt2[(size_t)f * 960 + p] = pack2(v0, v1);
    }
    if (t == 0) bias2[f] = (f < Fn) ? cb[f] : 0.f;
}

// ---------------------------------------------------------------------------
// prep_ub: Ub[g][f] = bf16(U[f][g]), [416][416], zero pad both dims.
// ---------------------------------------------------------------------------
__global__ __launch_bounds__(256) void prep_ub(
        const float* __restrict__ U, ushort16* __restrict__ Ub)
{
    const int g = blockIdx.x, t = threadIdx.x;
    uint32* orow = (uint32*)(Ub + (size_t)g * 416);
    for (int f2 = t; f2 < 208; f2 += 256) {
        int f = 2 * f2;
        float v0 = 0.f, v1 = 0.f;
        if (g < Fn) {
            if (f < Fn)     v0 = U[(size_t)f * Fn + g];
            if (f + 1 < Fn) v1 = U[(size_t)(f + 1) * Fn + g];
        }
        orow[f2] = pack2(v0, v1);
    }
}

// ---------------------------------------------------------------------------
// ec_gemm: EC[v][kk*416+f] = sum_e embbf[v][e] * Wt2[f][kk*320+e]  (bf16)
// 256v x 128f tile, grid (196 vt, 10 c). Combines the two proven levers:
//  - 3-deep counted-vmcnt pipeline (r6: +6us at occ1): wait vmcnt(3)
//    (next buffer's 3 loads stay in flight), vmcnt(0) only at ks=9.
//  - 2 blocks/CU (r3: 79us vs 86-92 at occ1): LDS = 3x(16+8)KB = 72KB.
// Per wave/step: 3 GLDS, 8 ds_read_b128, 16 MFMA (same ratio as r3 tile).
// Slot-reuse safety: slot (ks+2)%3 last READ at step ks-1; those reads
// complete before barrier(ks) -> stage-after-barrier(ks) race-free.
// Swapped-operand MFMA: D[f][v] -> 8B uint2 stores.
// ---------------------------------------------------------------------------
__global__ __launch_bounds__(512, 4) void ec_gemm(
        const char* __restrict__ embbf, const char* __restrict__ Wt2,
        char* __restrict__ EC)
{
    __shared__ __align__(16) char As[49152];   // 3 x 16KB (256 rows x 64B)
    __shared__ __align__(16) char Bs[24576];   // 3 x  8KB (128 rows x 64B)
    const int vt = blockIdx.x, c = blockIdx.y;
    const int t = threadIdx.x, lane = t & 63, w = t >> 6;
    const int v0 = vt * 256, c0 = c * 128;
    const int wr = w >> 1, wc = w & 1;         // 4x2 wave grid over 256x128
    const int fm = lane & 15;
    const int cg = ((lane & 3) - ((lane >> 3) & 3)) & 3;
    const int rl = lane >> 2;
    const int chunkOff = (((lane >> 4) + (fm >> 1)) & 3) * 16;

    const char* srcA[2];
#pragma unroll
    for (int i = 0; i < 2; ++i)
        srcA[i] = embbf + (size_t)(v0 + w * 32 + i * 16 + rl) * 640 + cg * 16;
    int n = c0 + w * 16 + rl;                  // B row (8 waves x 16 = 128)
    int kk = n / 416, f = n - kk * 416;
    if (n >= 1248) { kk = 0; f = 508; }        // zero row
    const char* srcB = Wt2 + (size_t)f * 1920 + kk * 640 + cg * 16;

    char* AsW = As + w * 2048;
    char* BsW = Bs + w * 1024;

    floatx4 acc[4][4];
    const floatx4 zz = {0.f, 0.f, 0.f, 0.f};
#pragma unroll
    for (int m = 0; m < 4; ++m)
#pragma unroll
        for (int nn = 0; nn < 4; ++nn) acc[m][nn] = zz;

#define ESTG(ko, buf) do {                                                    \
        const int _ko = (ko);                                                 \
        GLDS16(srcA[0] + _ko, AsW + (buf) * 16384);                           \
        GLDS16(srcA[1] + _ko, AsW + (buf) * 16384 + 1024);                    \
        GLDS16(srcB + _ko,    BsW + (buf) * 8192);                            \
    } while (0)

    ESTG(0, 0);
    ESTG(64, 1);

#pragma unroll
    for (int ks = 0; ks < 10; ++ks) {
        // wait for buf ks%3 (3 loads of buf ks+1 may stay in flight)
        if (ks == 9) asm volatile("s_waitcnt vmcnt(0)" ::: "memory");
        else         asm volatile("s_waitcnt vmcnt(3)" ::: "memory");
        __builtin_amdgcn_s_barrier();
        __builtin_amdgcn_sched_barrier(0);

        short8 af[4], bfv[4];
        const char* Ac = As + (ks % 3) * 16384;
        const char* Bc = Bs + (ks % 3) * 8192;
#pragma unroll
        for (int m = 0; m < 4; ++m)
            af[m] = *(const short8*)(Ac + (wr * 64 + m * 16 + fm) * 64 + chunkOff);
#pragma unroll
        for (int nn = 0; nn < 4; ++nn)
            bfv[nn] = *(const short8*)(Bc + (wc * 64 + nn * 16 + fm) * 64 + chunkOff);

        if (ks < 8) ESTG((ks + 2) * 64, (ks + 2) % 3);

        __builtin_amdgcn_s_setprio(1);
#pragma unroll
        for (int m = 0; m < 4; ++m)
#pragma unroll
            for (int nn = 0; nn < 4; ++nn)
                acc[m][nn] = __builtin_amdgcn_mfma_f32_16x16x32_bf16(
                    bfv[nn], af[m], acc[m][nn], 0, 0, 0);   // swapped: D[f][v]
        __builtin_amdgcn_s_setprio(0);
        __builtin_amdgcn_sched_barrier(0);   // pin body before next wait
    }
#undef ESTG

    // D[row=f][col=v]: 4 consecutive f per lane -> 8B stores.
#pragma unroll
    for (int m = 0; m < 4; ++m) {
        const int v = v0 + wr * 64 + m * 16 + fm;
#pragma unroll
        for (int nn = 0; nn < 4; ++nn) {
            const int f0 = c0 + wc * 64 + nn * 16 + ((lane >> 4) * 4);
            uint2 o;
            o.x = pack2(acc[m][nn][0], acc[m][nn][1]);
            o.y = pack2(acc[m][nn][2], acc[m][nn][3]);
            *(uint2*)(EC + (size_t)v * ECSTRIDE + f0 * 2) = o;
        }
    }
}

// ---------------------------------------------------------------------------
// gather: out[b][l][f] = bf16( EC[t(l-1)][0*416+f] + EC[t(l)][1*416+f]
//                            + EC[t(l+1)][2*416+f] + bias[f] )
// One thread per 16B chunk (52/row) — round-5 proven form (32B regressed).
// OOB token 0 (EC row 0 exactly zero). Merged Q+A launch.
// ---------------------------------------------------------------------------
static __device__ __forceinline__ void gather_one(
        const int* __restrict__ toks, const char* __restrict__ EC,
        const float* __restrict__ bias2, char* __restrict__ outb,
        int id, int L)
{
    const uint32 uid = (uint32)id;
    const int c = (int)(uid % 52u);
    const int r = (int)(uid / 52u);
    const int l = r & (L - 1), b = r / L;   // L is 512 or 128 (pow2)
    const int* tr = toks + (size_t)b * L;
    const int t0 = (l > 0)     ? tr[l - 1] : 0;
    const int t1 = tr[l];
    const int t2 = (l < L - 1) ? tr[l + 1] : 0;
    const uint4 x0 = *(const uint4*)(EC + (size_t)t0 * ECSTRIDE +        c * 16);
    const uint4 x1 = *(const uint4*)(EC + (size_t)t1 * ECSTRIDE +  832 + c * 16);
    const uint4 x2 = *(const uint4*)(EC + (size_t)t2 * ECSTRIDE + 1664 + c * 16);
    const float4 b0 = *(const float4*)(bias2 + c * 8);
    const float4 b1 = *(const float4*)(bias2 + c * 8 + 4);
    uint4 o;
    o.x = pack2(bf_lo(x0.x) + bf_lo(x1.x) + bf_lo(x2.x) + b0.x,
                bf_hi(x0.x) + bf_hi(x1.x) + bf_hi(x2.x) + b0.y);
    o.y = pack2(bf_lo(x0.y) + bf_lo(x1.y) + bf_lo(x2.y) + b0.z,
                bf_hi(x0.y) + bf_hi(x1.y) + bf_hi(x2.y) + b0.w);
    o.z = pack2(bf_lo(x0.z) + bf_lo(x1.z) + bf_lo(x2.z) + b1.x,
                bf_hi(x0.z) + bf_hi(x1.z) + bf_hi(x2.z) + b1.y);
    o.w = pack2(bf_lo(x0.w) + bf_lo(x1.w) + bf_lo(x2.w) + b1.z,
                bf_hi(x0.w) + bf_hi(x1.w) + bf_hi(x2.w) + b1.w);
    *(uint4*)(outb + (size_t)r * 832 + c * 16) = o;
}

#define GQB 1024
#define GAB 4096
__global__ __launch_bounds__(256) void gather_both(
        const int* __restrict__ question, const int* __restrict__ answer,
        const char* __restrict__ EC, const float* __restrict__ bias2,
        char* __restrict__ qb, char* __restrict__ ab, int nb)
{
    const int bx = blockIdx.x, t = threadIdx.x;
    if (bx < GQB) {
        const int total = nb * QLn * 52;
        for (int id = bx * 256 + t; id < total; id += GQB * 256)
            gather_one(question, EC, bias2, qb, id, QLn);
    } else {
        const int total = nb * ALn * 52;
        for (int id = (bx - GQB) * 256 + t; id < total; id += GAB * 256)
            gather_one(answer, EC, bias2, ab, id, ALn);
    }
}

// ---------------------------------------------------------------------------
// qp_gemm: Qp[b] = Q[b] (128x416, biased) x Ub (416 cols) -> [128][416] bf16.
// Per batch 2 blocks (nt): nt0 cols 0..256 <2,4,4,4>, nt1 cols 256..416
// <4,2,2,5>. K=416 (13 steps). XCD-affine decode: both nt of b share bx%8.
// ---------------------------------------------------------------------------
template<int NWM, int NWN, int MF, int NF, int BR>
static __device__ __forceinline__ void qp_tile(
        const char* __restrict__ Qb, const char* __restrict__ Ub,
        char* __restrict__ ob, int col0, char* As, char* Bs)
{
    const int t = threadIdx.x, lane = t & 63, w = t >> 6;
    const int wr = w / NWN, wc = w % NWN;
    const int fm = lane & 15;
    const int cg = ((lane & 3) - ((lane >> 3) & 3)) & 3;
    const int rl = lane >> 2;
    const int chunkOff = (((lane >> 4) + (fm >> 1)) & 3) * 16;

    const char* srcA = Qb + (size_t)(w * 16 + rl) * 832 + cg * 16;
    const char* srcB0; const char* srcB1 = 0;
    if (BR == 256) {
        srcB0 = Ub + (size_t)(col0 + w * 32 + rl) * 832 + cg * 16;
        srcB1 = srcB0 + (size_t)16 * 832;
    } else {
        srcB0 = Ub + (size_t)(col0 + w * 16 + rl) * 832 + cg * 16;
        srcB1 = Ub + (size_t)(col0 + 128 + w * 16 + rl) * 832 + cg * 16;
    }
    char* AsW = As + w * 1024;
    char* BsW0; char* BsW1;
    if (BR == 256) { BsW0 = Bs + w * 2048; BsW1 = BsW0 + 1024; }
    else           { BsW0 = Bs + w * 1024; BsW1 = Bs + 8192 + w * 1024; }
    const int BUFB = BR * 64;

    floatx4 acc[MF][NF];
    const floatx4 zz = {0.f, 0.f, 0.f, 0.f};
#pragma unroll
    for (int m = 0; m < MF; ++m)
#pragma unroll
        for (int n = 0; n < NF; ++n) acc[m][n] = zz;

#define QSTG(ko, buf) do {                                                    \
        const int _ko = (ko);                                                 \
        GLDS16(srcA + _ko, AsW + (buf) * 8192);                               \
        GLDS16(srcB0 + _ko, BsW0 + (buf) * BUFB);                             \
        if (BR == 256 || w < 2) GLDS16(srcB1 + _ko, BsW1 + (buf) * BUFB);     \
    } while (0)

    int cur = 0;
    QSTG(0, 0);
    __syncthreads();
    for (int ks = 0; ks < 13; ++ks) {
        const int nxt = cur ^ 1;
        if (ks < 12) QSTG((ks + 1) * 64, nxt);
        short8 af[MF], bfv[NF];
        const char* Ac = As + cur * 8192;
        const char* Bc = Bs + cur * BUFB;
#pragma unroll
        for (int m = 0; m < MF; ++m)
            af[m] = *(const short8*)(Ac + (wr * (MF * 16) + m * 16 + fm) * 64 + chunkOff);
#pragma unroll
        for (int n = 0; n < NF; ++n)
            bfv[n] = *(const short8*)(Bc + (wc * (NF * 16) + n * 16 + fm) * 64 + chunkOff);
        __builtin_amdgcn_s_setprio(1);
#pragma unroll
        for (int m = 0; m < MF; ++m)
#pragma unroll
            for (int n = 0; n < NF; ++n)
                acc[m][n] = __builtin_amdgcn_mfma_f32_16x16x32_bf16(
                    af[m], bfv[n], acc[m][n], 0, 0, 0);
        __builtin_amdgcn_s_setprio(0);
        __syncthreads();
        cur = nxt;
    }
#undef QSTG

#pragma unroll
    for (int m = 0; m < MF; ++m) {
        const int row = wr * (MF * 16) + m * 16 + ((lane >> 4) * 4);
#pragma unroll
        for (int n = 0; n < NF; ++n) {
            const int col = col0 + wc * (NF * 16) + n * 16 + fm;
#pragma unroll
            for (int r = 0; r < 4; ++r)
                *(ushort16*)(ob + (size_t)(row + r) * 832 + col * 2) =
                    f2bf(acc[m][n][r]);
        }
    }
}

__global__ __launch_bounds__(512) void qp_gemm(
        const char* __restrict__ qb, const char* __restrict__ Ub,
        char* __restrict__ qpb, int nb)
{
    __shared__ __align__(16) char As[16384];   // 2 x 128 x 64B
    __shared__ __align__(16) char Bs[32768];   // 2 x <=256 x 64B
    const int bx = blockIdx.x;
    const int xcd = bx & 7, rest = bx >> 3;
    const int nt = rest & 1, b = (rest >> 1) * 8 + xcd;
    if (b >= nb) return;
    const char* Qb = qb + (size_t)b * 106496;
    char* ob = qpb + (size_t)b * 106496;
    if (nt == 0)
        qp_tile<2, 4, 4, 4, 256>(Qb, Ub, ob, 0, As, Bs);
    else
        qp_tile<4, 2, 2, 5, 160>(Qb, Ub, ob, 256, As, Bs);
}

// ---------------------------------------------------------------------------
// fused_g: block (b, a-chunk c of 256). Gpre = Qp A^T (K=416).
// 256 thr, 4 waves (wave w owns 64 A-cols), 8x4 frags/wave (32 MFMA per
// 12 ds_reads per step). XCD-affine decode: both c of b share bx%8.
// colMax written DIRECTLY (each wave owns distinct cols); rowMax 2 partials.
// ---------------------------------------------------------------------------
__global__ __launch_bounds__(256) void fused_g(
        const ushort16* __restrict__ Qp,   // [nb][128][416]
        const ushort16* __restrict__ Av,   // [nb][512][416]
        float* __restrict__ rowPart,       // [nb][2][128]
        float* __restrict__ colMg,         // [nb][512]
        int nb)
{
    __shared__ __align__(16) char Qs[16384];    // 2 x 128 x 64B
    __shared__ __align__(16) char Asl[32768];   // 2 x 256 x 64B
    __shared__ float rowM4[128][4];

    const int t = threadIdx.x, lane = t & 63, w = t >> 6;   // w = wave col 0..3
    const int bx = blockIdx.x;
    const int xcd = bx & 7, rest = bx >> 3;
    const int c = rest & 1, b = (rest >> 1) * 8 + xcd;
    if (b >= nb) return;
    const int fm = lane & 15;
    const int cg = ((lane & 3) - ((lane >> 3) & 3)) & 3;
    const int rl = lane >> 2;
    const int chunkOff = (((lane >> 4) + (fm >> 1)) & 3) * 16;

    const char* Qpb = (const char*)Qp + (size_t)b * 106496;
    const char* Ab  = (const char*)Av + (size_t)b * 425984 + (size_t)c * 212992;
    const char* srcQ0 = Qpb + (size_t)(w * 16 + rl) * 832 + cg * 16;
    const char* srcQ1 = Qpb + (size_t)(64 + w * 16 + rl) * 832 + cg * 16;
    const char* srcA0 = Ab  + (size_t)(w * 64 + rl) * 832 + cg * 16;

    floatx4 acc[8][4];
    const floatx4 zz = {0.f, 0.f, 0.f, 0.f};
#pragma unroll
    for (int m = 0; m < 8; ++m)
#pragma unroll
        for (int n = 0; n < 4; ++n) acc[m][n] = zz;

#define FSTG(ko, buf) do {                                                    \
        const int _ko = (ko);                                                 \
        GLDS16(srcQ0 + _ko, Qs + (buf) * 8192 + w * 1024);                    \
        GLDS16(srcQ1 + _ko, Qs + (buf) * 8192 + 4096 + w * 1024);             \
        GLDS16(srcA0 + _ko,         Asl + (buf) * 16384 + w * 4096);          \
        GLDS16(srcA0 + 13312 + _ko, Asl + (buf) * 16384 + w * 4096 + 1024);   \
        GLDS16(srcA0 + 26624 + _ko, Asl + (buf) * 16384 + w * 4096 + 2048);   \
        GLDS16(srcA0 + 39936 + _ko, Asl + (buf) * 16384 + w * 4096 + 3072);   \
    } while (0)

    int cur = 0;
    FSTG(0, 0);
    __syncthreads();

    for (int ks = 0; ks < 13; ++ks) {
        const int nxt = cur ^ 1;
        if (ks < 12) FSTG((ks + 1) * 64, nxt);

        short8 qa[8], aa_[4];
        const char* Qc = Qs + cur * 8192;
        const char* Ac = Asl + cur * 16384;
#pragma unroll
        for (int m = 0; m < 8; ++m)
            qa[m] = *(const short8*)(Qc + (m * 16 + fm) * 64 + chunkOff);
#pragma unroll
        for (int n = 0; n < 4; ++n)
            aa_[n] = *(const short8*)(Ac + (w * 64 + n * 16 + fm) * 64 + chunkOff);
        __builtin_amdgcn_s_setprio(1);
#pragma unroll
        for (int m = 0; m < 8; ++m)
#pragma unroll
            for (int n = 0; n < 4; ++n)
                acc[m][n] = __builtin_amdgcn_mfma_f32_16x16x32_bf16(
                    qa[m], aa_[n], acc[m][n], 0, 0, 0);
        __builtin_amdgcn_s_setprio(0);
        __syncthreads();
        cur = nxt;
    }
#undef FSTG

    // rowMax partial (max over this wave's 64 cols), per wave -> rowM4[row][w]
#pragma unroll
    for (int m = 0; m < 8; ++m)
#pragma unroll
        for (int r = 0; r < 4; ++r) {
            float v = fmaxf(fmaxf(acc[m][0][r], acc[m][1][r]),
                            fmaxf(acc[m][2][r], acc[m][3][r]));
            v = fmaxf(v, __shfl_xor(v, 1));
            v = fmaxf(v, __shfl_xor(v, 2));
            v = fmaxf(v, __shfl_xor(v, 4));
            v = fmaxf(v, __shfl_xor(v, 8));
            if (fm == 0) rowM4[m * 16 + (lane >> 4) * 4 + r][w] = v;
        }
    // colMax: wave owns cols c*256 + w*64 + n*16 + fm -> write direct
#pragma unroll
    for (int n = 0; n < 4; ++n) {
        float v = -1e30f;
#pragma unroll
        for (int m = 0; m < 8; ++m)
#pragma unroll
            for (int r = 0; r < 4; ++r) v = fmaxf(v, acc[m][n][r]);
        v = fmaxf(v, __shfl_xor(v, 16));
        v = fmaxf(v, __shfl_xor(v, 32));
        if (lane < 16)
            colMg[(size_t)b * 512 + c * 256 + w * 64 + n * 16 + lane] = v;
    }
    __syncthreads();
    if (t < 128)
        rowPart[((size_t)b * 2 + c) * 128 + t] =
            fmaxf(fmaxf(rowM4[t][0], rowM4[t][1]),
                  fmaxf(rowM4[t][2], rowM4[t][3]));
}

// ---------------------------------------------------------------------------
// fused_pool: per-batch softmax over tanh(maxes) + pooling + cosine.
// 1024 threads; pooling loops split 4 ways over rows (serial 640 -> 160
// iters), partials combined in LDS before the cosine reduction.
// ---------------------------------------------------------------------------
static __device__ __forceinline__ float block_reduce_max_1k(float v, volatile float* red) {
    int t = threadIdx.x;
    red[t] = v; __syncthreads();
    for (int s = 512; s > 0; s >>= 1) {
        if (t < s) red[t] = fmaxf(red[t], red[t + s]);
        __syncthreads();
    }
    float r = red[0]; __syncthreads();
    return r;
}
static __device__ __forceinline__ float block_reduce_sum_1k(float v, volatile float* red) {
    int t = threadIdx.x;
    red[t] = v; __syncthreads();
    for (int s = 512; s > 0; s >>= 1) {
        if (t < s) red[t] = red[t] + red[t + s];
        __syncthreads();
    }
    float r = red[0]; __syncthreads();
    return r;
}

__global__ __launch_bounds__(1024) void fused_pool(
        const ushort16* __restrict__ Qv,   // [nb][128][416]
        const ushort16* __restrict__ Av,   // [nb][512][416]
        const float* __restrict__ rowPart, // [nb][2][128]
        const float* __restrict__ colMg,   // [nb][512]
        float* __restrict__ out)
{
    __shared__ float colv[ALn];
    __shared__ float roq[QLn];
    __shared__ float red[1024];
    __shared__ float part[4][4][208];   // [rq0,rq1,ra0,ra1][h][c]
    const int t = threadIdx.x, b = blockIdx.x;

    float v = -1e30f;
    if (t < QLn) {
        const float* rp = rowPart + (size_t)b * 256;
        v = tanhf(fmaxf(rp[t], rp[128 + t]));
    }
    float vmax = block_reduce_max_1k(v, red);
    float ex = (t < QLn) ? __expf(v - vmax) : 0.f;
    float ssum = block_reduce_sum_1k(ex, red);
    if (t < QLn) roq[t] = ex / ssum;

    float cv = (t < ALn) ? tanhf(colMg[(size_t)b * 512 + t]) : -1e30f;
    float cmax = block_reduce_max_1k(cv, red);
    float e0 = (t < ALn) ? __expf(cv - cmax) : 0.f;
    float csum = block_reduce_sum_1k(e0, red);
    if (t < ALn) colv[t] = e0 / csum;
    __syncthreads();

    if (t < 832) {
        const int h = t / 208, c = t - h * 208;
        float rq0 = 0.f, rq1 = 0.f, ra0 = 0.f, ra1 = 0.f;
        const uint32* Qb32 = (const uint32*)((const char*)Qv + (size_t)b * 106496);
#pragma unroll 4
        for (int q = h * 32; q < h * 32 + 32; ++q) {
            float wv = roq[q];
            uint32 u = Qb32[q * 208 + c];
            rq0 = fmaf(bf_lo(u), wv, rq0);
            rq1 = fmaf(bf_hi(u), wv, rq1);
        }
        const uint32* Ab32 = (const uint32*)((const char*)Av + (size_t)b * 425984);
#pragma unroll 4
        for (int a = h * 128; a < h * 128 + 128; ++a) {
            float wv = colv[a];
            uint32 u = Ab32[a * 208 + c];
            ra0 = fmaf(bf_lo(u), wv, ra0);
            ra1 = fmaf(bf_hi(u), wv, ra1);
        }
        part[0][h][c] = rq0; part[1][h][c] = rq1;
        part[2][h][c] = ra0; part[3][h][c] = ra1;
    }
    __syncthreads();

    float dd = 0.f, qq = 0.f, aam = 0.f;
    if (t < 208) {
        float q0 = part[0][0][t] + part[0][1][t] + part[0][2][t] + part[0][3][t];
        float q1 = part[1][0][t] + part[1][1][t] + part[1][2][t] + part[1][3][t];
        float a0 = part[2][0][t] + part[2][1][t] + part[2][2][t] + part[2][3][t];
        float a1 = part[3][0][t] + part[3][1][t] + part[3][2][t] + part[3][3][t];
        dd  = q0 * a0 + q1 * a1;
        qq  = q0 * q0 + q1 * q1;
        aam = a0 * a0 + a1 * a1;
    }
    dd  = block_reduce_sum_1k(dd, red);
    qq  = block_reduce_sum_1k(qq, red);
    aam = block_reduce_sum_1k(aam, red);
    if (t == 0) {
        float nq = fmaxf(sqrtf(qq), 1e-8f);
        float na = fmaxf(sqrtf(aam), 1e-8f);
        out[b] = dd / (nq * na);
    }
}

// ---------------------------------------------------------------------------
// launch — ws: [Wt2 | bias2 | Ub | EC | overlay{embbf | per-chunk bufs}]
// embbf is only needed to build EC; per-chunk buffers overlay it afterwards.
// ---------------------------------------------------------------------------
extern "C" void kernel_launch(void* const* d_in, const int* in_sizes, int n_in,
                              void* d_out, int out_size, void* d_ws, size_t ws_size,
                              hipStream_t stream)
{
    const int*   question = (const int*)d_in[0];
    const int*   answer   = (const int*)d_in[1];
    const float* emb      = (const float*)d_in[2];
    const float* conv_w   = (const float*)d_in[3];
    const float* conv_b   = (const float*)d_in[4];
    const float* U        = (const float*)d_in[5];
    float* out = (float*)d_out;
    char* ws = (char*)d_ws;

    const size_t WT2B   = (size_t)512 * 960 * 2;             // 983,040
    const size_t UBB    = (size_t)416 * 416 * 2;             // 346,112
    const size_t ECB    = (size_t)ECROWS * ECSTRIDE;         // 128,450,560
    const size_t FIXED0 = WT2B + 2048 + UBB + ECB;           // 129,781,760
    const size_t QB     = (size_t)QLn * OW * 2;              // 106,496
    const size_t AB     = (size_t)ALn * OW * 2;              // 425,984
    const size_t MXB    = 4096;
    const size_t PER_B  = 2 * QB + AB + MXB;                 // 643,072

    size_t avail = (ws_size > FIXED0) ? (ws_size - FIXED0) : 0;
    int CB = (int)(avail / PER_B);
    if (CB > Bb) CB = Bb;
    if (CB < 1)  CB = 1;
    int nch = (Bb + CB - 1) / CB;
    int CBe = (Bb + nch - 1) / nch;      // balanced chunk size (<= CB)

    char*  wt2   = ws;
    float* bias2 = (float*)(ws + WT2B);
    char*  ub    = ws + WT2B + 2048;
    char*  EC    = ws + WT2B + 2048 + UBB;
    char*  embbf = ws + FIXED0;           // overlay: used only for ec_gemm
    char*  qb    = ws + FIXED0;           // overlay after ec_gemm completes
    char*  qpb   = qb  + (size_t)CB * QB;
    char*  ab    = qpb + (size_t)CB * QB;
    float* rowP  = (float*)(ab + (size_t)CB * AB);
    float* colM  = rowP + (size_t)CB * 512;

    embcvt_kernel<<<NV, 128, 0, stream>>>(emb, embbf);
    prep_wt<<<512, 256, 0, stream>>>(conv_w, conv_b, (ushort16*)wt2, bias2);
    prep_ub<<<416, 256, 0, stream>>>(U, (ushort16*)ub);
    ec_gemm<<<dim3(196, 10), 512, 0, stream>>>(embbf, wt2, EC);

    for (int b0 = 0; b0 < Bb; b0 += CBe) {
        int nb = (Bb - b0 < CBe) ? (Bb - b0) : CBe;
        int nb8 = (nb + 7) / 8;
        gather_both<<<GQB + GAB, 256, 0, stream>>>(
            question + (size_t)b0 * QLn, answer + (size_t)b0 * ALn,
            EC, bias2, qb, ab, nb);
        qp_gemm<<<nb8 * 16, 512, 0, stream>>>(qb, ub, qpb, nb);
        fused_g<<<nb8 * 16, 256, 0, stream>>>((const ushort16*)qpb, (const ushort16*)ab,
                                              rowP, colM, nb);
        fused_pool<<<nb, 1024, 0, stream>>>((const ushort16*)qb, (const ushort16*)ab,
                                            rowP, colM, out + b0);
    }
}

// Round 8
// 614.904 us; speedup vs baseline: 1.0170x; 1.0170x over previous
//
#include <hip/hip_runtime.h>
#include <math.h>

typedef unsigned int   uint32;
typedef unsigned short ushort16;
typedef __attribute__((ext_vector_type(8))) short  short8;   // 8 bf16 (MFMA A/B frag)
typedef __attribute__((ext_vector_type(4))) float  floatx4;  // MFMA C/D frag

// Problem dims
#define Bb   512
#define QLn  128
#define ALn  512
#define En   300
#define Fn   400
#define OW   416      // packed output width: 400 real + 16 zero (832 B = 13*64)
#define EPAD 320      // e padded 300 -> 320 per shift
#define NV   50001
#define ECROWS 50176  // 196*256 padded vocab rows
#define ECSTRIDE 2560 // 1280 cols * 2B (3*416 used + 32 pad)

typedef const __attribute__((address_space(1))) unsigned int guint_t;
typedef __attribute__((address_space(3))) unsigned int luint_t;
#define GLDS16(g, l) __builtin_amdgcn_global_load_lds((guint_t*)(g), (luint_t*)(l), 16, 0, 0)

static __device__ __forceinline__ float bf_lo(uint32 u) { return __uint_as_float(u << 16); }
static __device__ __forceinline__ float bf_hi(uint32 u) { return __uint_as_float(u & 0xffff0000u); }
static __device__ __forceinline__ ushort16 f2bf(float f) {
    uint32 u = __float_as_uint(f);
    uint32 r = (u + 0x7fffu + ((u >> 16) & 1u)) >> 16;   // RNE
    return (ushort16)r;
}
static __device__ __forceinline__ uint32 pack2(float a, float b) {
    return (uint32)f2bf(a) | ((uint32)f2bf(b) << 16);
}

// ---------------------------------------------------------------------------
// embcvt: embbf[v][0..320) = bf16(emb[v][0..300)), e>=300 zero.
// ---------------------------------------------------------------------------
__global__ __launch_bounds__(128) void embcvt_kernel(
        const float* __restrict__ emb, char* __restrict__ embbf)
{
    const int r = blockIdx.x, j = threadIdx.x;
    const float* er = emb + (size_t)r * En;
    uint32* orow = (uint32*)(embbf + (size_t)r * 640);
    for (int d = j; d < 160; d += 128) {
        uint32 v = 0;
        if (d < 150) {
            float2 f2v = *(const float2*)(er + 2 * d);
            v = pack2(f2v.x, f2v.y);
        }
        orow[d] = v;
    }
}

// ---------------------------------------------------------------------------
// prep_wt: Wt2[f][p] = W[f][e*3+kk] (p = kk*320+e), bf16, zero pad; bias2.
// Rows f in [400,512) are fully zero (used as zero-rows by ec_gemm pad).
// ---------------------------------------------------------------------------
__global__ __launch_bounds__(256) void prep_wt(
        const float* __restrict__ W, const float* __restrict__ cb,
        ushort16* __restrict__ Wt2, float* __restrict__ bias2)
{
    const int f = blockIdx.x, t = threadIdx.x;
    for (int p2 = t; p2 < 480; p2 += 256) {
        int p = 2 * p2;
        float v0 = 0.f, v1 = 0.f;
        if (f < Fn) {
            int kk = p / EPAD, e = p - kk * EPAD;
            if (e < En)     v0 = W[(size_t)f * 900 + e * 3 + kk];
            if (e + 1 < En) v1 = W[(size_t)f * 900 + (e + 1) * 3 + kk];
        }
        *(uint32*)&Wt2[(size_t)f * 960 + p] = pack2(v0, v1);
    }
    if (t == 0) bias2[f] = (f < Fn) ? cb[f] : 0.f;
}

// ---------------------------------------------------------------------------
// prep_ub: Ub[g][f] = bf16(U[f][g]), [416][416], zero pad both dims.
// ---------------------------------------------------------------------------
__global__ __launch_bounds__(256) void prep_ub(
        const float* __restrict__ U, ushort16* __restrict__ Ub)
{
    const int g = blockIdx.x, t = threadIdx.x;
    uint32* orow = (uint32*)(Ub + (size_t)g * 416);
    for (int f2 = t; f2 < 208; f2 += 256) {
        int f = 2 * f2;
        float v0 = 0.f, v1 = 0.f;
        if (g < Fn) {
            if (f < Fn)     v0 = U[(size_t)f * Fn + g];
            if (f + 1 < Fn) v1 = U[(size_t)(f + 1) * Fn + g];
        }
        orow[f2] = pack2(v0, v1);
    }
}

// ---------------------------------------------------------------------------
// ec_gemm: EC[v][kk*416+f] = sum_e embbf[v][e] * Wt2[f][kk*320+e]  (bf16)
// EXACT round-3 proven structure (79us): 256x256 tile, 2-phase dbuf, 64KB
// LDS (2 blocks/CU), grid dim3(196 vt, 5 c). Ledger: this beat A-resident
// (92), XCD-affine (92), 3-deep occ1 (86), 3-deep occ2 narrow (99).
// ONE isolated change vs r3: swapped-operand MFMA (D[f][v]) + uint2 stores
// (32 x 8B per thread vs 128 x 2B) — layout verified through r5-r7 benches.
// B rows map n -> (kk, f): ptr = Wt2 + f*1920 + kk*640. n>=1248 -> zero row.
// ---------------------------------------------------------------------------
__global__ __launch_bounds__(512) void ec_gemm(
        const char* __restrict__ embbf, const char* __restrict__ Wt2,
        char* __restrict__ EC)
{
    __shared__ __align__(16) char As[32768];   // 2 x 256 rows x 64B
    __shared__ __align__(16) char Bs[32768];
    const int t = threadIdx.x, lane = t & 63, w = t >> 6;
    const int v0 = blockIdx.x * 256, c0 = blockIdx.y * 256;
    const int wr = w >> 2, wc = w & 3;
    const int fm = lane & 15;
    const int cg = ((lane & 3) - ((lane >> 3) & 3)) & 3;
    const int rl = lane >> 2;
    const int chunkOff = (((lane >> 4) + (fm >> 1)) & 3) * 16;

    const char* srcA[2];
    const char* srcB[2];
#pragma unroll
    for (int i = 0; i < 2; ++i) {
        srcA[i] = embbf + (size_t)(v0 + w * 32 + i * 16 + rl) * 640 + cg * 16;
        int n = c0 + w * 32 + i * 16 + rl;
        int kk = n / 416, f = n - kk * 416;
        if (n >= 1248) { kk = 0; f = 508; }   // zero row
        srcB[i] = Wt2 + (size_t)f * 1920 + kk * 640 + cg * 16;
    }
    char* AsW = As + w * 2048;
    char* BsW = Bs + w * 2048;

    floatx4 acc[8][4];
    const floatx4 zz = {0.f, 0.f, 0.f, 0.f};
#pragma unroll
    for (int m = 0; m < 8; ++m)
#pragma unroll
        for (int n = 0; n < 4; ++n) acc[m][n] = zz;

#define ESTG(ko, buf) do {                                                    \
        const int _ko = (ko); const int _bo = (buf) * 16384;                  \
        GLDS16(srcA[0] + _ko, AsW + _bo);                                     \
        GLDS16(srcA[1] + _ko, AsW + _bo + 1024);                              \
        GLDS16(srcB[0] + _ko, BsW + _bo);                                     \
        GLDS16(srcB[1] + _ko, BsW + _bo + 1024);                              \
    } while (0)

    int cur = 0;
    ESTG(0, 0);
    __syncthreads();
    for (int ks = 0; ks < 10; ++ks) {
        const int nxt = cur ^ 1;
        if (ks < 9) ESTG((ks + 1) * 64, nxt);
        short8 af[8], bfv[4];
        const char* Ac = As + cur * 16384;
        const char* Bc = Bs + cur * 16384;
#pragma unroll
        for (int m = 0; m < 8; ++m)
            af[m] = *(const short8*)(Ac + (wr * 128 + m * 16 + fm) * 64 + chunkOff);
#pragma unroll
        for (int n = 0; n < 4; ++n)
            bfv[n] = *(const short8*)(Bc + (wc * 64 + n * 16 + fm) * 64 + chunkOff);
        __builtin_amdgcn_s_setprio(1);
#pragma unroll
        for (int m = 0; m < 8; ++m)
#pragma unroll
            for (int n = 0; n < 4; ++n)
                acc[m][n] = __builtin_amdgcn_mfma_f32_16x16x32_bf16(
                    bfv[n], af[m], acc[m][n], 0, 0, 0);   // swapped: D[f][v]
        __builtin_amdgcn_s_setprio(0);
        __syncthreads();
        cur = nxt;
    }
#undef ESTG

    // D[row=f][col=v]: row = (lane>>4)*4 + r within bfv[n]'s 16-block,
    // col = fm within af[m]'s 16-block -> 4 consecutive f per lane: 8B stores.
#pragma unroll
    for (int m = 0; m < 8; ++m) {
        const int v = v0 + wr * 128 + m * 16 + fm;
#pragma unroll
        for (int n = 0; n < 4; ++n) {
            const int f0 = c0 + wc * 64 + n * 16 + ((lane >> 4) * 4);
            uint2 o;
            o.x = pack2(acc[m][n][0], acc[m][n][1]);
            o.y = pack2(acc[m][n][2], acc[m][n][3]);
            *(uint2*)(EC + (size_t)v * ECSTRIDE + f0 * 2) = o;
        }
    }
}

// ---------------------------------------------------------------------------
// gather: out[b][l][f] = bf16( EC[t(l-1)][0*416+f] + EC[t(l)][1*416+f]
//                            + EC[t(l+1)][2*416+f] + bias[f] )
// One thread per 16B chunk (52/row) — round-5 proven form (32B regressed).
// OOB token 0 (EC row 0 exactly zero). Merged Q+A launch.
// ---------------------------------------------------------------------------
static __device__ __forceinline__ void gather_one(
        const int* __restrict__ toks, const char* __restrict__ EC,
        const float* __restrict__ bias2, char* __restrict__ outb,
        int id, int L)
{
    const uint32 uid = (uint32)id;
    const int c = (int)(uid % 52u);
    const int r = (int)(uid / 52u);
    const int l = r & (L - 1), b = r / L;   // L is 512 or 128 (pow2)
    const int* tr = toks + (size_t)b * L;
    const int t0 = (l > 0)     ? tr[l - 1] : 0;
    const int t1 = tr[l];
    const int t2 = (l < L - 1) ? tr[l + 1] : 0;
    const uint4 x0 = *(const uint4*)(EC + (size_t)t0 * ECSTRIDE +        c * 16);
    const uint4 x1 = *(const uint4*)(EC + (size_t)t1 * ECSTRIDE +  832 + c * 16);
    const uint4 x2 = *(const uint4*)(EC + (size_t)t2 * ECSTRIDE + 1664 + c * 16);
    const float4 b0 = *(const float4*)(bias2 + c * 8);
    const float4 b1 = *(const float4*)(bias2 + c * 8 + 4);
    uint4 o;
    o.x = pack2(bf_lo(x0.x) + bf_lo(x1.x) + bf_lo(x2.x) + b0.x,
                bf_hi(x0.x) + bf_hi(x1.x) + bf_hi(x2.x) + b0.y);
    o.y = pack2(bf_lo(x0.y) + bf_lo(x1.y) + bf_lo(x2.y) + b0.z,
                bf_hi(x0.y) + bf_hi(x1.y) + bf_hi(x2.y) + b0.w);
    o.z = pack2(bf_lo(x0.z) + bf_lo(x1.z) + bf_lo(x2.z) + b1.x,
                bf_hi(x0.z) + bf_hi(x1.z) + bf_hi(x2.z) + b1.y);
    o.w = pack2(bf_lo(x0.w) + bf_lo(x1.w) + bf_lo(x2.w) + b1.z,
                bf_hi(x0.w) + bf_hi(x1.w) + bf_hi(x2.w) + b1.w);
    *(uint4*)(outb + (size_t)r * 832 + c * 16) = o;
}

#define GQB 1024
#define GAB 4096
__global__ __launch_bounds__(256) void gather_both(
        const int* __restrict__ question, const int* __restrict__ answer,
        const char* __restrict__ EC, const float* __restrict__ bias2,
        char* __restrict__ qb, char* __restrict__ ab, int nb)
{
    const int bx = blockIdx.x, t = threadIdx.x;
    if (bx < GQB) {
        const int total = nb * QLn * 52;
        for (int id = bx * 256 + t; id < total; id += GQB * 256)
            gather_one(question, EC, bias2, qb, id, QLn);
    } else {
        const int total = nb * ALn * 52;
        for (int id = (bx - GQB) * 256 + t; id < total; id += GAB * 256)
            gather_one(answer, EC, bias2, ab, id, ALn);
    }
}

// ---------------------------------------------------------------------------
// qp_gemm: Qp[b] = Q[b] (128x416, biased) x Ub (416 cols) -> [128][416] bf16.
// Per batch 2 blocks (nt): nt0 cols 0..256 <2,4,4,4>, nt1 cols 256..416
// <4,2,2,5>. K=416 (13 steps). XCD-affine decode: both nt of b share bx%8.
// ---------------------------------------------------------------------------
template<int NWM, int NWN, int MF, int NF, int BR>
static __device__ __forceinline__ void qp_tile(
        const char* __restrict__ Qb, const char* __restrict__ Ub,
        char* __restrict__ ob, int col0, char* As, char* Bs)
{
    const int t = threadIdx.x, lane = t & 63, w = t >> 6;
    const int wr = w / NWN, wc = w % NWN;
    const int fm = lane & 15;
    const int cg = ((lane & 3) - ((lane >> 3) & 3)) & 3;
    const int rl = lane >> 2;
    const int chunkOff = (((lane >> 4) + (fm >> 1)) & 3) * 16;

    const char* srcA = Qb + (size_t)(w * 16 + rl) * 832 + cg * 16;
    const char* srcB0; const char* srcB1 = 0;
    if (BR == 256) {
        srcB0 = Ub + (size_t)(col0 + w * 32 + rl) * 832 + cg * 16;
        srcB1 = srcB0 + (size_t)16 * 832;
    } else {
        srcB0 = Ub + (size_t)(col0 + w * 16 + rl) * 832 + cg * 16;
        srcB1 = Ub + (size_t)(col0 + 128 + w * 16 + rl) * 832 + cg * 16;
    }
    char* AsW = As + w * 1024;
    char* BsW0; char* BsW1;
    if (BR == 256) { BsW0 = Bs + w * 2048; BsW1 = BsW0 + 1024; }
    else           { BsW0 = Bs + w * 1024; BsW1 = Bs + 8192 + w * 1024; }
    const int BUFB = BR * 64;

    floatx4 acc[MF][NF];
    const floatx4 zz = {0.f, 0.f, 0.f, 0.f};
#pragma unroll
    for (int m = 0; m < MF; ++m)
#pragma unroll
        for (int n = 0; n < NF; ++n) acc[m][n] = zz;

#define QSTG(ko, buf) do {                                                    \
        const int _ko = (ko);                                                 \
        GLDS16(srcA + _ko, AsW + (buf) * 8192);                               \
        GLDS16(srcB0 + _ko, BsW0 + (buf) * BUFB);                             \
        if (BR == 256 || w < 2) GLDS16(srcB1 + _ko, BsW1 + (buf) * BUFB);     \
    } while (0)

    int cur = 0;
    QSTG(0, 0);
    __syncthreads();
    for (int ks = 0; ks < 13; ++ks) {
        const int nxt = cur ^ 1;
        if (ks < 12) QSTG((ks + 1) * 64, nxt);
        short8 af[MF], bfv[NF];
        const char* Ac = As + cur * 8192;
        const char* Bc = Bs + cur * BUFB;
#pragma unroll
        for (int m = 0; m < MF; ++m)
            af[m] = *(const short8*)(Ac + (wr * (MF * 16) + m * 16 + fm) * 64 + chunkOff);
#pragma unroll
        for (int n = 0; n < NF; ++n)
            bfv[n] = *(const short8*)(Bc + (wc * (NF * 16) + n * 16 + fm) * 64 + chunkOff);
        __builtin_amdgcn_s_setprio(1);
#pragma unroll
        for (int m = 0; m < MF; ++m)
#pragma unroll
            for (int n = 0; n < NF; ++n)
                acc[m][n] = __builtin_amdgcn_mfma_f32_16x16x32_bf16(
                    af[m], bfv[n], acc[m][n], 0, 0, 0);
        __builtin_amdgcn_s_setprio(0);
        __syncthreads();
        cur = nxt;
    }
#undef QSTG

#pragma unroll
    for (int m = 0; m < MF; ++m) {
        const int row = wr * (MF * 16) + m * 16 + ((lane >> 4) * 4);
#pragma unroll
        for (int n = 0; n < NF; ++n) {
            const int col = col0 + wc * (NF * 16) + n * 16 + fm;
#pragma unroll
            for (int r = 0; r < 4; ++r)
                *(ushort16*)(ob + (size_t)(row + r) * 832 + col * 2) =
                    f2bf(acc[m][n][r]);
        }
    }
}

__global__ __launch_bounds__(512) void qp_gemm(
        const char* __restrict__ qb, const char* __restrict__ Ub,
        char* __restrict__ qpb, int nb)
{
    __shared__ __align__(16) char As[16384];   // 2 x 128 x 64B
    __shared__ __align__(16) char Bs[32768];   // 2 x <=256 x 64B
    const int bx = blockIdx.x;
    const int xcd = bx & 7, rest = bx >> 3;
    const int nt = rest & 1, b = (rest >> 1) * 8 + xcd;
    if (b >= nb) return;
    const char* Qb = qb + (size_t)b * 106496;
    char* ob = qpb + (size_t)b * 106496;
    if (nt == 0)
        qp_tile<2, 4, 4, 4, 256>(Qb, Ub, ob, 0, As, Bs);
    else
        qp_tile<4, 2, 2, 5, 160>(Qb, Ub, ob, 256, As, Bs);
}

// ---------------------------------------------------------------------------
// fused_g: block (b, a-chunk c of 256). Gpre = Qp A^T (K=416).
// 256 thr, 4 waves (wave w owns 64 A-cols), 8x4 frags/wave (32 MFMA per
// 12 ds_reads per step). XCD-affine decode: both c of b share bx%8.
// colMax written DIRECTLY (each wave owns distinct cols); rowMax 2 partials.
// ---------------------------------------------------------------------------
__global__ __launch_bounds__(256) void fused_g(
        const ushort16* __restrict__ Qp,   // [nb][128][416]
        const ushort16* __restrict__ Av,   // [nb][512][416]
        float* __restrict__ rowPart,       // [nb][2][128]
        float* __restrict__ colMg,         // [nb][512]
        int nb)
{
    __shared__ __align__(16) char Qs[16384];    // 2 x 128 x 64B
    __shared__ __align__(16) char Asl[32768];   // 2 x 256 x 64B
    __shared__ float rowM4[128][4];

    const int t = threadIdx.x, lane = t & 63, w = t >> 6;   // w = wave col 0..3
    const int bx = blockIdx.x;
    const int xcd = bx & 7, rest = bx >> 3;
    const int c = rest & 1, b = (rest >> 1) * 8 + xcd;
    if (b >= nb) return;
    const int fm = lane & 15;
    const int cg = ((lane & 3) - ((lane >> 3) & 3)) & 3;
    const int rl = lane >> 2;
    const int chunkOff = (((lane >> 4) + (fm >> 1)) & 3) * 16;

    const char* Qpb = (const char*)Qp + (size_t)b * 106496;
    const char* Ab  = (const char*)Av + (size_t)b * 425984 + (size_t)c * 212992;
    const char* srcQ0 = Qpb + (size_t)(w * 16 + rl) * 832 + cg * 16;
    const char* srcQ1 = Qpb + (size_t)(64 + w * 16 + rl) * 832 + cg * 16;
    const char* srcA0 = Ab  + (size_t)(w * 64 + rl) * 832 + cg * 16;

    floatx4 acc[8][4];
    const floatx4 zz = {0.f, 0.f, 0.f, 0.f};
#pragma unroll
    for (int m = 0; m < 8; ++m)
#pragma unroll
        for (int n = 0; n < 4; ++n) acc[m][n] = zz;

#define FSTG(ko, buf) do {                                                    \
        const int _ko = (ko);                                                 \
        GLDS16(srcQ0 + _ko, Qs + (buf) * 8192 + w * 1024);                    \
        GLDS16(srcQ1 + _ko, Qs + (buf) * 8192 + 4096 + w * 1024);             \
        GLDS16(srcA0 + _ko,         Asl + (buf) * 16384 + w * 4096);          \
        GLDS16(srcA0 + 13312 + _ko, Asl + (buf) * 16384 + w * 4096 + 1024);   \
        GLDS16(srcA0 + 26624 + _ko, Asl + (buf) * 16384 + w * 4096 + 2048);   \
        GLDS16(srcA0 + 39936 + _ko, Asl + (buf) * 16384 + w * 4096 + 3072);   \
    } while (0)

    int cur = 0;
    FSTG(0, 0);
    __syncthreads();

    for (int ks = 0; ks < 13; ++ks) {
        const int nxt = cur ^ 1;
        if (ks < 12) FSTG((ks + 1) * 64, nxt);

        short8 qa[8], aa_[4];
        const char* Qc = Qs + cur * 8192;
        const char* Ac = Asl + cur * 16384;
#pragma unroll
        for (int m = 0; m < 8; ++m)
            qa[m] = *(const short8*)(Qc + (m * 16 + fm) * 64 + chunkOff);
#pragma unroll
        for (int n = 0; n < 4; ++n)
            aa_[n] = *(const short8*)(Ac + (w * 64 + n * 16 + fm) * 64 + chunkOff);
        __builtin_amdgcn_s_setprio(1);
#pragma unroll
        for (int m = 0; m < 8; ++m)
#pragma unroll
            for (int n = 0; n < 4; ++n)
                acc[m][n] = __builtin_amdgcn_mfma_f32_16x16x32_bf16(
                    qa[m], aa_[n], acc[m][n], 0, 0, 0);
        __builtin_amdgcn_s_setprio(0);
        __syncthreads();
        cur = nxt;
    }
#undef FSTG

    // rowMax partial (max over this wave's 64 cols), per wave -> rowM4[row][w]
#pragma unroll
    for (int m = 0; m < 8; ++m)
#pragma unroll
        for (int r = 0; r < 4; ++r) {
            float v = fmaxf(fmaxf(acc[m][0][r], acc[m][1][r]),
                            fmaxf(acc[m][2][r], acc[m][3][r]));
            v = fmaxf(v, __shfl_xor(v, 1));
            v = fmaxf(v, __shfl_xor(v, 2));
            v = fmaxf(v, __shfl_xor(v, 4));
            v = fmaxf(v, __shfl_xor(v, 8));
            if (fm == 0) rowM4[m * 16 + (lane >> 4) * 4 + r][w] = v;
        }
    // colMax: wave owns cols c*256 + w*64 + n*16 + fm -> write direct
#pragma unroll
    for (int n = 0; n < 4; ++n) {
        float v = -1e30f;
#pragma unroll
        for (int m = 0; m < 8; ++m)
#pragma unroll
            for (int r = 0; r < 4; ++r) v = fmaxf(v, acc[m][n][r]);
        v = fmaxf(v, __shfl_xor(v, 16));
        v = fmaxf(v, __shfl_xor(v, 32));
        if (lane < 16)
            colMg[(size_t)b * 512 + c * 256 + w * 64 + n * 16 + lane] = v;
    }
    __syncthreads();
    if (t < 128)
        rowPart[((size_t)b * 2 + c) * 128 + t] =
            fmaxf(fmaxf(rowM4[t][0], rowM4[t][1]),
                  fmaxf(rowM4[t][2], rowM4[t][3]));
}

// ---------------------------------------------------------------------------
// fused_pool: per-batch softmax over tanh(maxes) + pooling + cosine.
// 1024 threads; pooling loops split 4 ways over rows (serial 640 -> 160
// iters), partials combined in LDS before the cosine reduction.
// ---------------------------------------------------------------------------
static __device__ __forceinline__ float block_reduce_max_1k(float v, volatile float* red) {
    int t = threadIdx.x;
    red[t] = v; __syncthreads();
    for (int s = 512; s > 0; s >>= 1) {
        if (t < s) red[t] = fmaxf(red[t], red[t + s]);
        __syncthreads();
    }
    float r = red[0]; __syncthreads();
    return r;
}
static __device__ __forceinline__ float block_reduce_sum_1k(float v, volatile float* red) {
    int t = threadIdx.x;
    red[t] = v; __syncthreads();
    for (int s = 512; s > 0; s >>= 1) {
        if (t < s) red[t] = red[t] + red[t + s];
        __syncthreads();
    }
    float r = red[0]; __syncthreads();
    return r;
}

__global__ __launch_bounds__(1024) void fused_pool(
        const ushort16* __restrict__ Qv,   // [nb][128][416]
        const ushort16* __restrict__ Av,   // [nb][512][416]
        const float* __restrict__ rowPart, // [nb][2][128]
        const float* __restrict__ colMg,   // [nb][512]
        float* __restrict__ out)
{
    __shared__ float colv[ALn];
    __shared__ float roq[QLn];
    __shared__ float red[1024];
    __shared__ float part[4][4][208];   // [rq0,rq1,ra0,ra1][h][c]
    const int t = threadIdx.x, b = blockIdx.x;

    float v = -1e30f;
    if (t < QLn) {
        const float* rp = rowPart + (size_t)b * 256;
        v = tanhf(fmaxf(rp[t], rp[128 + t]));
    }
    float vmax = block_reduce_max_1k(v, red);
    float ex = (t < QLn) ? __expf(v - vmax) : 0.f;
    float ssum = block_reduce_sum_1k(ex, red);
    if (t < QLn) roq[t] = ex / ssum;

    float cv = (t < ALn) ? tanhf(colMg[(size_t)b * 512 + t]) : -1e30f;
    float cmax = block_reduce_max_1k(cv, red);
    float e0 = (t < ALn) ? __expf(cv - cmax) : 0.f;
    float csum = block_reduce_sum_1k(e0, red);
    if (t < ALn) colv[t] = e0 / csum;
    __syncthreads();

    if (t < 832) {
        const int h = t / 208, c = t - h * 208;
        float rq0 = 0.f, rq1 = 0.f, ra0 = 0.f, ra1 = 0.f;
        const uint32* Qb32 = (const uint32*)((const char*)Qv + (size_t)b * 106496);
#pragma unroll 4
        for (int q = h * 32; q < h * 32 + 32; ++q) {
            float wv = roq[q];
            uint32 u = Qb32[q * 208 + c];
            rq0 = fmaf(bf_lo(u), wv, rq0);
            rq1 = fmaf(bf_hi(u), wv, rq1);
        }
        const uint32* Ab32 = (const uint32*)((const char*)Av + (size_t)b * 425984);
#pragma unroll 4
        for (int a = h * 128; a < h * 128 + 128; ++a) {
            float wv = colv[a];
            uint32 u = Ab32[a * 208 + c];
            ra0 = fmaf(bf_lo(u), wv, ra0);
            ra1 = fmaf(bf_hi(u), wv, ra1);
        }
        part[0][h][c] = rq0; part[1][h][c] = rq1;
        part[2][h][c] = ra0; part[3][h][c] = ra1;
    }
    __syncthreads();

    float dd = 0.f, qq = 0.f, aam = 0.f;
    if (t < 208) {
        float q0 = part[0][0][t] + part[0][1][t] + part[0][2][t] + part[0][3][t];
        float q1 = part[1][0][t] + part[1][1][t] + part[1][2][t] + part[1][3][t];
        float a0 = part[2][0][t] + part[2][1][t] + part[2][2][t] + part[2][3][t];
        float a1 = part[3][0][t] + part[3][1][t] + part[3][2][t] + part[3][3][t];
        dd  = q0 * a0 + q1 * a1;
        qq  = q0 * q0 + q1 * q1;
        aam = a0 * a0 + a1 * a1;
    }
    dd  = block_reduce_sum_1k(dd, red);
    qq  = block_reduce_sum_1k(qq, red);
    aam = block_reduce_sum_1k(aam, red);
    if (t == 0) {
        float nq = fmaxf(sqrtf(qq), 1e-8f);
        float na = fmaxf(sqrtf(aam), 1e-8f);
        out[b] = dd / (nq * na);
    }
}

// ---------------------------------------------------------------------------
// launch — ws: [Wt2 | bias2 | Ub | EC | overlay{embbf | per-chunk bufs}]
// embbf is only needed to build EC; per-chunk buffers overlay it afterwards.
// ---------------------------------------------------------------------------
extern "C" void kernel_launch(void* const* d_in, const int* in_sizes, int n_in,
                              void* d_out, int out_size, void* d_ws, size_t ws_size,
                              hipStream_t stream)
{
    const int*   question = (const int*)d_in[0];
    const int*   answer   = (const int*)d_in[1];
    const float* emb      = (const float*)d_in[2];
    const float* conv_w   = (const float*)d_in[3];
    const float* conv_b   = (const float*)d_in[4];
    const float* U        = (const float*)d_in[5];
    float* out = (float*)d_out;
    char* ws = (char*)d_ws;

    const size_t WT2B   = (size_t)512 * 960 * 2;             // 983,040
    const size_t UBB    = (size_t)416 * 416 * 2;             // 346,112
    const size_t ECB    = (size_t)ECROWS * ECSTRIDE;         // 128,450,560
    const size_t FIXED0 = WT2B + 2048 + UBB + ECB;           // 129,781,760
    const size_t QB     = (size_t)QLn * OW * 2;              // 106,496
    const size_t AB     = (size_t)ALn * OW * 2;              // 425,984
    const size_t MXB    = 4096;
    const size_t PER_B  = 2 * QB + AB + MXB;                 // 643,072

    size_t avail = (ws_size > FIXED0) ? (ws_size - FIXED0) : 0;
    int CB = (int)(avail / PER_B);
    if (CB > Bb) CB = Bb;
    if (CB < 1)  CB = 1;
    int nch = (Bb + CB - 1) / CB;
    int CBe = (Bb + nch - 1) / nch;      // balanced chunk size (<= CB)

    char*  wt2   = ws;
    float* bias2 = (float*)(ws + WT2B);
    char*  ub    = ws + WT2B + 2048;
    char*  EC    = ws + WT2B + 2048 + UBB;
    char*  embbf = ws + FIXED0;           // overlay: used only for ec_gemm
    char*  qb    = ws + FIXED0;           // overlay after ec_gemm completes
    char*  qpb   = qb  + (size_t)CB * QB;
    char*  ab    = qpb + (size_t)CB * QB;
    float* rowP  = (float*)(ab + (size_t)CB * AB);
    float* colM  = rowP + (size_t)CB * 512;

    embcvt_kernel<<<NV, 128, 0, stream>>>(emb, embbf);
    prep_wt<<<512, 256, 0, stream>>>(conv_w, conv_b, (ushort16*)wt2, bias2);
    prep_ub<<<416, 256, 0, stream>>>(U, (ushort16*)ub);
    ec_gemm<<<dim3(196, 5), 512, 0, stream>>>(embbf, wt2, EC);

    for (int b0 = 0; b0 < Bb; b0 += CBe) {
        int nb = (Bb - b0 < CBe) ? (Bb - b0) : CBe;
        int nb8 = (nb + 7) / 8;
        gather_both<<<GQB + GAB, 256, 0, stream>>>(
            question + (size_t)b0 * QLn, answer + (size_t)b0 * ALn,
            EC, bias2, qb, ab, nb);
        qp_gemm<<<nb8 * 16, 512, 0, stream>>>(qb, ub, qpb, nb);
        fused_g<<<nb8 * 16, 256, 0, stream>>>((const ushort16*)qpb, (const ushort16*)ab,
                                              rowP, colM, nb);
        fused_pool<<<nb, 1024, 0, stream>>>((const ushort16*)qb, (const ushort16*)ab,
                                            rowP, colM, out + b0);
    }
}

// Round 9
// 568.019 us; speedup vs baseline: 1.1009x; 1.0825x over previous
//
#include <hip/hip_runtime.h>
#include <math.h>

typedef unsigned int   uint32;
typedef unsigned short ushort16;
typedef __attribute__((ext_vector_type(8))) short  short8;   // 8 bf16 (MFMA A/B frag)
typedef __attribute__((ext_vector_type(4))) float  floatx4;  // MFMA C/D frag

// Problem dims
#define Bb   512
#define QLn  128
#define ALn  512
#define En   300
#define Fn   400
#define OW   416      // packed output width: 400 real + 16 zero (832 B = 13*64)
#define EPAD 320      // e padded 300 -> 320 per shift
#define NV   50001
#define ECROWS 50176  // 196*256 padded vocab rows
#define ECSTRIDE 2560 // 1280 cols * 2B (3*416 used + 32 pad)

typedef const __attribute__((address_space(1))) unsigned int guint_t;
typedef __attribute__((address_space(3))) unsigned int luint_t;
#define GLDS16(g, l) __builtin_amdgcn_global_load_lds((guint_t*)(g), (luint_t*)(l), 16, 0, 0)

static __device__ __forceinline__ float bf_lo(uint32 u) { return __uint_as_float(u << 16); }
static __device__ __forceinline__ float bf_hi(uint32 u) { return __uint_as_float(u & 0xffff0000u); }
static __device__ __forceinline__ ushort16 f2bf(float f) {
    uint32 u = __float_as_uint(f);
    uint32 r = (u + 0x7fffu + ((u >> 16) & 1u)) >> 16;   // RNE
    return (ushort16)r;
}
static __device__ __forceinline__ uint32 pack2(float a, float b) {
    return (uint32)f2bf(a) | ((uint32)f2bf(b) << 16);
}

// ---------------------------------------------------------------------------
// embcvt: embbf[v][0..320) = bf16(emb[v][0..300)), e>=300 zero.
// ---------------------------------------------------------------------------
__global__ __launch_bounds__(128) void embcvt_kernel(
        const float* __restrict__ emb, char* __restrict__ embbf)
{
    const int r = blockIdx.x, j = threadIdx.x;
    const float* er = emb + (size_t)r * En;
    uint32* orow = (uint32*)(embbf + (size_t)r * 640);
    for (int d = j; d < 160; d += 128) {
        uint32 v = 0;
        if (d < 150) {
            float2 f2v = *(const float2*)(er + 2 * d);
            v = pack2(f2v.x, f2v.y);
        }
        orow[d] = v;
    }
}

// ---------------------------------------------------------------------------
// prep_wt: Wt2[f][p] = W[f][e*3+kk] (p = kk*320+e), bf16, zero pad; bias2.
// Rows f in [400,512) are fully zero (used as zero-rows by ec_gemm pad).
// ---------------------------------------------------------------------------
__global__ __launch_bounds__(256) void prep_wt(
        const float* __restrict__ W, const float* __restrict__ cb,
        ushort16* __restrict__ Wt2, float* __restrict__ bias2)
{
    const int f = blockIdx.x, t = threadIdx.x;
    for (int p2 = t; p2 < 480; p2 += 256) {
        int p = 2 * p2;
        float v0 = 0.f, v1 = 0.f;
        if (f < Fn) {
            int kk = p / EPAD, e = p - kk * EPAD;
            if (e < En)     v0 = W[(size_t)f * 900 + e * 3 + kk];
            if (e + 1 < En) v1 = W[(size_t)f * 900 + (e + 1) * 3 + kk];
        }
        *(uint32*)&Wt2[(size_t)f * 960 + p] = pack2(v0, v1);
    }
    if (t == 0) bias2[f] = (f < Fn) ? cb[f] : 0.f;
}

// ---------------------------------------------------------------------------
// prep_ub: Ub[g][f] = bf16(U[f][g]), [416][416], zero pad both dims.
// ---------------------------------------------------------------------------
__global__ __launch_bounds__(256) void prep_ub(
        const float* __restrict__ U, ushort16* __restrict__ Ub)
{
    const int g = blockIdx.x, t = threadIdx.x;
    uint32* orow = (uint32*)(Ub + (size_t)g * 416);
    for (int f2 = t; f2 < 208; f2 += 256) {
        int f = 2 * f2;
        float v0 = 0.f, v1 = 0.f;
        if (g < Fn) {
            if (f < Fn)     v0 = U[(size_t)f * Fn + g];
            if (f + 1 < Fn) v1 = U[(size_t)(f + 1) * Fn + g];
        }
        orow[f2] = pack2(v0, v1);
    }
}

// ---------------------------------------------------------------------------
// ec_gemm: EC[v][kk*416+f] = sum_e embbf[v][e] * Wt2[f][kk*320+e]  (bf16)
// BYTE-EXACT round-3 structure (measured 79us): 256x256 tile, 2-phase dbuf,
// 64KB LDS (2 blocks/CU), grid dim3(196,5), NORMAL operand order, scalar 2B
// stores. r8 isolated the swapped+uint2 variant at 89-91us (hbm 2.7->2.4
// TB/s, WRITE +1.8MB) -> reverted.
// B rows map n -> (kk, f): ptr = Wt2 + f*1920 + kk*640. n>=1248 -> zero row.
// ---------------------------------------------------------------------------
__global__ __launch_bounds__(512) void ec_gemm(
        const char* __restrict__ embbf, const char* __restrict__ Wt2,
        char* __restrict__ EC)
{
    __shared__ __align__(16) char As[32768];   // 2 x 256 rows x 64B
    __shared__ __align__(16) char Bs[32768];
    const int t = threadIdx.x, lane = t & 63, w = t >> 6;
    const int v0 = blockIdx.x * 256, c0 = blockIdx.y * 256;
    const int wr = w >> 2, wc = w & 3;
    const int fm = lane & 15;
    const int cg = ((lane & 3) - ((lane >> 3) & 3)) & 3;
    const int rl = lane >> 2;
    const int chunkOff = (((lane >> 4) + (fm >> 1)) & 3) * 16;

    const char* srcA[2];
    const char* srcB[2];
#pragma unroll
    for (int i = 0; i < 2; ++i) {
        srcA[i] = embbf + (size_t)(v0 + w * 32 + i * 16 + rl) * 640 + cg * 16;
        int n = c0 + w * 32 + i * 16 + rl;
        int kk = n / 416, f = n - kk * 416;
        if (n >= 1248) { kk = 0; f = 508; }   // zero row
        srcB[i] = Wt2 + (size_t)f * 1920 + kk * 640 + cg * 16;
    }
    char* AsW = As + w * 2048;
    char* BsW = Bs + w * 2048;

    floatx4 acc[8][4];
    const floatx4 zz = {0.f, 0.f, 0.f, 0.f};
#pragma unroll
    for (int m = 0; m < 8; ++m)
#pragma unroll
        for (int n = 0; n < 4; ++n) acc[m][n] = zz;

#define ESTG(ko, buf) do {                                                    \
        const int _ko = (ko); const int _bo = (buf) * 16384;                  \
        GLDS16(srcA[0] + _ko, AsW + _bo);                                     \
        GLDS16(srcA[1] + _ko, AsW + _bo + 1024);                              \
        GLDS16(srcB[0] + _ko, BsW + _bo);                                     \
        GLDS16(srcB[1] + _ko, BsW + _bo + 1024);                              \
    } while (0)

    int cur = 0;
    ESTG(0, 0);
    __syncthreads();
    for (int ks = 0; ks < 10; ++ks) {
        const int nxt = cur ^ 1;
        if (ks < 9) ESTG((ks + 1) * 64, nxt);
        short8 af[8], bfv[4];
        const char* Ac = As + cur * 16384;
        const char* Bc = Bs + cur * 16384;
#pragma unroll
        for (int m = 0; m < 8; ++m)
            af[m] = *(const short8*)(Ac + (wr * 128 + m * 16 + fm) * 64 + chunkOff);
#pragma unroll
        for (int n = 0; n < 4; ++n)
            bfv[n] = *(const short8*)(Bc + (wc * 64 + n * 16 + fm) * 64 + chunkOff);
        __builtin_amdgcn_s_setprio(1);
#pragma unroll
        for (int m = 0; m < 8; ++m)
#pragma unroll
            for (int n = 0; n < 4; ++n)
                acc[m][n] = __builtin_amdgcn_mfma_f32_16x16x32_bf16(
                    af[m], bfv[n], acc[m][n], 0, 0, 0);
        __builtin_amdgcn_s_setprio(0);
        __syncthreads();
        cur = nxt;
    }
#undef ESTG

#pragma unroll
    for (int m = 0; m < 8; ++m) {
        const int v = v0 + wr * 128 + m * 16 + ((lane >> 4) * 4);
#pragma unroll
        for (int n = 0; n < 4; ++n) {
            const int col = c0 + wc * 64 + n * 16 + fm;
#pragma unroll
            for (int r = 0; r < 4; ++r)
                *(ushort16*)(EC + (size_t)(v + r) * ECSTRIDE + col * 2) =
                    f2bf(acc[m][n][r]);
        }
    }
}

// ---------------------------------------------------------------------------
// gather: out[b][l][f] = bf16( EC[t(l-1)][0*416+f] + EC[t(l)][1*416+f]
//                            + EC[t(l+1)][2*416+f] + bias[f] )
// One thread per 16B chunk (52/row) — round-5 proven form.
// ---------------------------------------------------------------------------
static __device__ __forceinline__ void gather_one(
        const int* __restrict__ toks, const char* __restrict__ EC,
        const float* __restrict__ bias2, char* __restrict__ outb,
        int id, int L)
{
    const uint32 uid = (uint32)id;
    const int c = (int)(uid % 52u);
    const int r = (int)(uid / 52u);
    const int l = r & (L - 1), b = r / L;   // L is 512 or 128 (pow2)
    const int* tr = toks + (size_t)b * L;
    const int t0 = (l > 0)     ? tr[l - 1] : 0;
    const int t1 = tr[l];
    const int t2 = (l < L - 1) ? tr[l + 1] : 0;
    const uint4 x0 = *(const uint4*)(EC + (size_t)t0 * ECSTRIDE +        c * 16);
    const uint4 x1 = *(const uint4*)(EC + (size_t)t1 * ECSTRIDE +  832 + c * 16);
    const uint4 x2 = *(const uint4*)(EC + (size_t)t2 * ECSTRIDE + 1664 + c * 16);
    const float4 b0 = *(const float4*)(bias2 + c * 8);
    const float4 b1 = *(const float4*)(bias2 + c * 8 + 4);
    uint4 o;
    o.x = pack2(bf_lo(x0.x) + bf_lo(x1.x) + bf_lo(x2.x) + b0.x,
                bf_hi(x0.x) + bf_hi(x1.x) + bf_hi(x2.x) + b0.y);
    o.y = pack2(bf_lo(x0.y) + bf_lo(x1.y) + bf_lo(x2.y) + b0.z,
                bf_hi(x0.y) + bf_hi(x1.y) + bf_hi(x2.y) + b0.w);
    o.z = pack2(bf_lo(x0.z) + bf_lo(x1.z) + bf_lo(x2.z) + b1.x,
                bf_hi(x0.z) + bf_hi(x1.z) + bf_hi(x2.z) + b1.y);
    o.w = pack2(bf_lo(x0.w) + bf_lo(x1.w) + bf_lo(x2.w) + b1.z,
                bf_hi(x0.w) + bf_hi(x1.w) + bf_hi(x2.w) + b1.w);
    *(uint4*)(outb + (size_t)r * 832 + c * 16) = o;
}

#define GQB 1024
#define GAB 4096
__global__ __launch_bounds__(256) void gather_both(
        const int* __restrict__ question, const int* __restrict__ answer,
        const char* __restrict__ EC, const float* __restrict__ bias2,
        char* __restrict__ qb, char* __restrict__ ab, int nb)
{
    const int bx = blockIdx.x, t = threadIdx.x;
    if (bx < GQB) {
        const int total = nb * QLn * 52;
        for (int id = bx * 256 + t; id < total; id += GQB * 256)
            gather_one(question, EC, bias2, qb, id, QLn);
    } else {
        const int total = nb * ALn * 52;
        for (int id = (bx - GQB) * 256 + t; id < total; id += GAB * 256)
            gather_one(answer, EC, bias2, ab, id, ALn);
    }
}

// ---------------------------------------------------------------------------
// qp_gemm: Qp[b] = Q[b] (128x416, biased) x Ub (416 cols) -> [128][416] bf16.
// Per batch 2 blocks (nt): nt0 cols 0..256 <2,4,4,4>, nt1 cols 256..416
// <4,2,2,5>. K=416 (13 steps). XCD-affine decode: both nt of b share bx%8.
// ---------------------------------------------------------------------------
template<int NWM, int NWN, int MF, int NF, int BR>
static __device__ __forceinline__ void qp_tile(
        const char* __restrict__ Qb, const char* __restrict__ Ub,
        char* __restrict__ ob, int col0, char* As, char* Bs)
{
    const int t = threadIdx.x, lane = t & 63, w = t >> 6;
    const int wr = w / NWN, wc = w % NWN;
    const int fm = lane & 15;
    const int cg = ((lane & 3) - ((lane >> 3) & 3)) & 3;
    const int rl = lane >> 2;
    const int chunkOff = (((lane >> 4) + (fm >> 1)) & 3) * 16;

    const char* srcA = Qb + (size_t)(w * 16 + rl) * 832 + cg * 16;
    const char* srcB0; const char* srcB1 = 0;
    if (BR == 256) {
        srcB0 = Ub + (size_t)(col0 + w * 32 + rl) * 832 + cg * 16;
        srcB1 = srcB0 + (size_t)16 * 832;
    } else {
        srcB0 = Ub + (size_t)(col0 + w * 16 + rl) * 832 + cg * 16;
        srcB1 = Ub + (size_t)(col0 + 128 + w * 16 + rl) * 832 + cg * 16;
    }
    char* AsW = As + w * 1024;
    char* BsW0; char* BsW1;
    if (BR == 256) { BsW0 = Bs + w * 2048; BsW1 = BsW0 + 1024; }
    else           { BsW0 = Bs + w * 1024; BsW1 = Bs + 8192 + w * 1024; }
    const int BUFB = BR * 64;

    floatx4 acc[MF][NF];
    const floatx4 zz = {0.f, 0.f, 0.f, 0.f};
#pragma unroll
    for (int m = 0; m < MF; ++m)
#pragma unroll
        for (int n = 0; n < NF; ++n) acc[m][n] = zz;

#define QSTG(ko, buf) do {                                                    \
        const int _ko = (ko);                                                 \
        GLDS16(srcA + _ko, AsW + (buf) * 8192);                               \
        GLDS16(srcB0 + _ko, BsW0 + (buf) * BUFB);                             \
        if (BR == 256 || w < 2) GLDS16(srcB1 + _ko, BsW1 + (buf) * BUFB);     \
    } while (0)

    int cur = 0;
    QSTG(0, 0);
    __syncthreads();
    for (int ks = 0; ks < 13; ++ks) {
        const int nxt = cur ^ 1;
        if (ks < 12) QSTG((ks + 1) * 64, nxt);
        short8 af[MF], bfv[NF];
        const char* Ac = As + cur * 8192;
        const char* Bc = Bs + cur * BUFB;
#pragma unroll
        for (int m = 0; m < MF; ++m)
            af[m] = *(const short8*)(Ac + (wr * (MF * 16) + m * 16 + fm) * 64 + chunkOff);
#pragma unroll
        for (int n = 0; n < NF; ++n)
            bfv[n] = *(const short8*)(Bc + (wc * (NF * 16) + n * 16 + fm) * 64 + chunkOff);
        __builtin_amdgcn_s_setprio(1);
#pragma unroll
        for (int m = 0; m < MF; ++m)
#pragma unroll
            for (int n = 0; n < NF; ++n)
                acc[m][n] = __builtin_amdgcn_mfma_f32_16x16x32_bf16(
                    af[m], bfv[n], acc[m][n], 0, 0, 0);
        __builtin_amdgcn_s_setprio(0);
        __syncthreads();
        cur = nxt;
    }
#undef QSTG

#pragma unroll
    for (int m = 0; m < MF; ++m) {
        const int row = wr * (MF * 16) + m * 16 + ((lane >> 4) * 4);
#pragma unroll
        for (int n = 0; n < NF; ++n) {
            const int col = col0 + wc * (NF * 16) + n * 16 + fm;
#pragma unroll
            for (int r = 0; r < 4; ++r)
                *(ushort16*)(ob + (size_t)(row + r) * 832 + col * 2) =
                    f2bf(acc[m][n][r]);
        }
    }
}

__global__ __launch_bounds__(512) void qp_gemm(
        const char* __restrict__ qb, const char* __restrict__ Ub,
        char* __restrict__ qpb, int nb)
{
    __shared__ __align__(16) char As[16384];   // 2 x 128 x 64B
    __shared__ __align__(16) char Bs[32768];   // 2 x <=256 x 64B
    const int bx = blockIdx.x;
    const int xcd = bx & 7, rest = bx >> 3;
    const int nt = rest & 1, b = (rest >> 1) * 8 + xcd;
    if (b >= nb) return;
    const char* Qb = qb + (size_t)b * 106496;
    char* ob = qpb + (size_t)b * 106496;
    if (nt == 0)
        qp_tile<2, 4, 4, 4, 256>(Qb, Ub, ob, 0, As, Bs);
    else
        qp_tile<4, 2, 2, 5, 160>(Qb, Ub, ob, 256, As, Bs);
}

// ---------------------------------------------------------------------------
// fused_g (M-split): block (b, c, mh). Gpre = Qp[mh-half] A[c-half]^T, K=416.
// 256 thr, 4 waves (wave w owns 64 A-cols), 4x4 frags/wave (16 MFMA per 8
// ds_reads/step). Grid nb*4 (~416 blocks at CBe=103, was 206) and 42KB LDS
// -> 3 blocks/CU co-residency: fixes the partial-grid tail seen at nch=5.
// rowPart[b][c][mh*64+row]; colMg[b][mh][512] partials (pool maxes mh).
// ---------------------------------------------------------------------------
__global__ __launch_bounds__(256) void fused_g(
        const ushort16* __restrict__ Qp,   // [nb][128][416]
        const ushort16* __restrict__ Av,   // [nb][512][416]
        float* __restrict__ rowPart,       // [nb][2][128]
        float* __restrict__ colMg,         // [nb][2][512]
        int nb)
{
    __shared__ __align__(16) char Qs[8192];     // 2 x 64 x 64B
    __shared__ __align__(16) char Asl[32768];   // 2 x 256 x 64B
    __shared__ float rowM4[64][4];

    const int t = threadIdx.x, lane = t & 63, w = t >> 6;   // w = wave col 0..3
    const int bx = blockIdx.x;
    const int xcd = bx & 7, rest = bx >> 3;
    const int c = rest & 1, mh = (rest >> 1) & 1, b = (rest >> 2) * 8 + xcd;
    if (b >= nb) return;
    const int fm = lane & 15;
    const int cg = ((lane & 3) - ((lane >> 3) & 3)) & 3;
    const int rl = lane >> 2;
    const int chunkOff = (((lane >> 4) + (fm >> 1)) & 3) * 16;

    const char* Qpb = (const char*)Qp + (size_t)b * 106496 + (size_t)mh * 64 * 832;
    const char* Ab  = (const char*)Av + (size_t)b * 425984 + (size_t)c * 212992;
    const char* srcQ  = Qpb + (size_t)(w * 16 + rl) * 832 + cg * 16;
    const char* srcA0 = Ab  + (size_t)(w * 64 + rl) * 832 + cg * 16;

    floatx4 acc[4][4];
    const floatx4 zz = {0.f, 0.f, 0.f, 0.f};
#pragma unroll
    for (int m = 0; m < 4; ++m)
#pragma unroll
        for (int n = 0; n < 4; ++n) acc[m][n] = zz;

#define FSTG(ko, buf) do {                                                    \
        const int _ko = (ko);                                                 \
        GLDS16(srcQ + _ko,          Qs  + (buf) * 4096  + w * 1024);          \
        GLDS16(srcA0 + _ko,         Asl + (buf) * 16384 + w * 4096);          \
        GLDS16(srcA0 + 13312 + _ko, Asl + (buf) * 16384 + w * 4096 + 1024);   \
        GLDS16(srcA0 + 26624 + _ko, Asl + (buf) * 16384 + w * 4096 + 2048);   \
        GLDS16(srcA0 + 39936 + _ko, Asl + (buf) * 16384 + w * 4096 + 3072);   \
    } while (0)

    int cur = 0;
    FSTG(0, 0);
    __syncthreads();

    for (int ks = 0; ks < 13; ++ks) {
        const int nxt = cur ^ 1;
        if (ks < 12) FSTG((ks + 1) * 64, nxt);

        short8 qa[4], aa_[4];
        const char* Qc = Qs + cur * 4096;
        const char* Ac = Asl + cur * 16384;
#pragma unroll
        for (int m = 0; m < 4; ++m)
            qa[m] = *(const short8*)(Qc + (m * 16 + fm) * 64 + chunkOff);
#pragma unroll
        for (int n = 0; n < 4; ++n)
            aa_[n] = *(const short8*)(Ac + (w * 64 + n * 16 + fm) * 64 + chunkOff);
        __builtin_amdgcn_s_setprio(1);
#pragma unroll
        for (int m = 0; m < 4; ++m)
#pragma unroll
            for (int n = 0; n < 4; ++n)
                acc[m][n] = __builtin_amdgcn_mfma_f32_16x16x32_bf16(
                    qa[m], aa_[n], acc[m][n], 0, 0, 0);
        __builtin_amdgcn_s_setprio(0);
        __syncthreads();
        cur = nxt;
    }
#undef FSTG

    // rowMax partial (max over this wave's 64 A-cols) -> rowM4[row][w]
#pragma unroll
    for (int m = 0; m < 4; ++m)
#pragma unroll
        for (int r = 0; r < 4; ++r) {
            float v = fmaxf(fmaxf(acc[m][0][r], acc[m][1][r]),
                            fmaxf(acc[m][2][r], acc[m][3][r]));
            v = fmaxf(v, __shfl_xor(v, 1));
            v = fmaxf(v, __shfl_xor(v, 2));
            v = fmaxf(v, __shfl_xor(v, 4));
            v = fmaxf(v, __shfl_xor(v, 8));
            if (fm == 0) rowM4[m * 16 + (lane >> 4) * 4 + r][w] = v;
        }
    // colMax (partial over this mh-half): wave owns cols c*256+w*64+n*16+fm
#pragma unroll
    for (int n = 0; n < 4; ++n) {
        float v = -1e30f;
#pragma unroll
        for (int m = 0; m < 4; ++m)
#pragma unroll
            for (int r = 0; r < 4; ++r) v = fmaxf(v, acc[m][n][r]);
        v = fmaxf(v, __shfl_xor(v, 16));
        v = fmaxf(v, __shfl_xor(v, 32));
        if (lane < 16)
            colMg[((size_t)b * 2 + mh) * 512 + c * 256 + w * 64 + n * 16 + lane] = v;
    }
    __syncthreads();
    if (t < 64)
        rowPart[((size_t)b * 2 + c) * 128 + mh * 64 + t] =
            fmaxf(fmaxf(rowM4[t][0], rowM4[t][1]),
                  fmaxf(rowM4[t][2], rowM4[t][3]));
}

// ---------------------------------------------------------------------------
// pool_a: block (b, quarter), 512 thr. Redundantly computes the softmax
// weights (cheap) then pools its quarter of Q (32 rows) and A (128 rows)
// into per-f partial vectors -> scratch[b][qtr][4][208].
// Grid nb*4 (~412 blocks, was 103 at 40% CU util).
// ---------------------------------------------------------------------------
static __device__ __forceinline__ float red_max_512(float v, volatile float* red) {
    int t = threadIdx.x;
    red[t] = v; __syncthreads();
    for (int s = 256; s > 0; s >>= 1) {
        if (t < s) red[t] = fmaxf(red[t], red[t + s]);
        __syncthreads();
    }
    float r = red[0]; __syncthreads();
    return r;
}
static __device__ __forceinline__ float red_sum_512(float v, volatile float* red) {
    int t = threadIdx.x;
    red[t] = v; __syncthreads();
    for (int s = 256; s > 0; s >>= 1) {
        if (t < s) red[t] = red[t] + red[t + s];
        __syncthreads();
    }
    float r = red[0]; __syncthreads();
    return r;
}

__global__ __launch_bounds__(512) void pool_a(
        const ushort16* __restrict__ Qv,   // [nb][128][416]
        const ushort16* __restrict__ Av,   // [nb][512][416]
        const float* __restrict__ rowPart, // [nb][2][128]
        const float* __restrict__ colMg,   // [nb][2][512]
        float* __restrict__ scratch,       // [nb][4][4][208]
        int nb)
{
    __shared__ float colv[ALn];
    __shared__ float roq[QLn];
    __shared__ float red[512];
    __shared__ float part[2][4][208];
    const int t = threadIdx.x, bx = blockIdx.x;
    const int qtr = bx & 3, b = bx >> 2;

    float v = -1e30f;
    if (t < QLn) {
        const float* rp = rowPart + (size_t)b * 256;
        v = tanhf(fmaxf(rp[t], rp[128 + t]));
    }
    float vmax = red_max_512(v, red);
    float ex = (t < QLn) ? __expf(v - vmax) : 0.f;
    float ssum = red_sum_512(ex, red);
    if (t < QLn) roq[t] = ex / ssum;

    const float* cm = colMg + (size_t)b * 1024;
    float cv = tanhf(fmaxf(cm[t], cm[512 + t]));
    float cmax = red_max_512(cv, red);
    float e0 = __expf(cv - cmax);
    float csum = red_sum_512(e0, red);
    colv[t] = e0 / csum;
    __syncthreads();

    if (t < 416) {
        const int half = t / 208, c = t - half * 208;
        float rq0 = 0.f, rq1 = 0.f, ra0 = 0.f, ra1 = 0.f;
        const uint32* Qb32 = (const uint32*)((const char*)Qv + (size_t)b * 106496);
        const int q0r = qtr * 32 + half * 16;
#pragma unroll 4
        for (int q = q0r; q < q0r + 16; ++q) {
            float wv = roq[q];
            uint32 u = Qb32[q * 208 + c];
            rq0 = fmaf(bf_lo(u), wv, rq0);
            rq1 = fmaf(bf_hi(u), wv, rq1);
        }
        const uint32* Ab32 = (const uint32*)((const char*)Av + (size_t)b * 425984);
        const int a0r = qtr * 128 + half * 64;
#pragma unroll 4
        for (int a = a0r; a < a0r + 64; ++a) {
            float wv = colv[a];
            uint32 u = Ab32[a * 208 + c];
            ra0 = fmaf(bf_lo(u), wv, ra0);
            ra1 = fmaf(bf_hi(u), wv, ra1);
        }
        part[half][0][c] = rq0; part[half][1][c] = rq1;
        part[half][2][c] = ra0; part[half][3][c] = ra1;
    }
    __syncthreads();

    if (t < 208) {
        float* sc = scratch + ((size_t)b * 4 + qtr) * 832;
        sc[t]       = part[0][0][t] + part[1][0][t];
        sc[208 + t] = part[0][1][t] + part[1][1][t];
        sc[416 + t] = part[0][2][t] + part[1][2][t];
        sc[624 + t] = part[0][3][t] + part[1][3][t];
    }
}

// pool_b: combine quarters + cosine. Grid nb, 256 thr (tiny).
static __device__ __forceinline__ float red_sum_256(float v, volatile float* red) {
    int t = threadIdx.x;
    red[t] = v; __syncthreads();
    for (int s = 128; s > 0; s >>= 1) {
        if (t < s) red[t] = red[t] + red[t + s];
        __syncthreads();
    }
    float r = red[0]; __syncthreads();
    return r;
}

__global__ __launch_bounds__(256) void pool_b(
        const float* __restrict__ scratch, float* __restrict__ out, int nb)
{
    __shared__ float red[256];
    const int t = threadIdx.x, b = blockIdx.x;
    float dd = 0.f, qq = 0.f, aam = 0.f;
    if (t < 208) {
        float q0 = 0.f, q1 = 0.f, a0 = 0.f, a1 = 0.f;
#pragma unroll
        for (int qtr = 0; qtr < 4; ++qtr) {
            const float* sc = scratch + ((size_t)b * 4 + qtr) * 832;
            q0 += sc[t]; q1 += sc[208 + t];
            a0 += sc[416 + t]; a1 += sc[624 + t];
        }
        dd  = q0 * a0 + q1 * a1;
        qq  = q0 * q0 + q1 * q1;
        aam = a0 * a0 + a1 * a1;
    }
    dd  = red_sum_256(dd, red);
    qq  = red_sum_256(qq, red);
    aam = red_sum_256(aam, red);
    if (t == 0) {
        float nq = fmaxf(sqrtf(qq), 1e-8f);
        float na = fmaxf(sqrtf(aam), 1e-8f);
        out[b] = dd / (nq * na);
    }
}

// ---------------------------------------------------------------------------
// launch — ws: [Wt2 | bias2 | Ub | EC | overlay{embbf | per-chunk bufs}]
// per-batch aux: rowPart 1KB + colMg 4KB + scratch 13312B <= MXB 20480.
// ---------------------------------------------------------------------------
extern "C" void kernel_launch(void* const* d_in, const int* in_sizes, int n_in,
                              void* d_out, int out_size, void* d_ws, size_t ws_size,
                              hipStream_t stream)
{
    const int*   question = (const int*)d_in[0];
    const int*   answer   = (const int*)d_in[1];
    const float* emb      = (const float*)d_in[2];
    const float* conv_w   = (const float*)d_in[3];
    const float* conv_b   = (const float*)d_in[4];
    const float* U        = (const float*)d_in[5];
    float* out = (float*)d_out;
    char* ws = (char*)d_ws;

    const size_t WT2B   = (size_t)512 * 960 * 2;             // 983,040
    const size_t UBB    = (size_t)416 * 416 * 2;             // 346,112
    const size_t ECB    = (size_t)ECROWS * ECSTRIDE;         // 128,450,560
    const size_t FIXED0 = WT2B + 2048 + UBB + ECB;           // 129,781,760
    const size_t QB     = (size_t)QLn * OW * 2;              // 106,496
    const size_t AB     = (size_t)ALn * OW * 2;              // 425,984
    const size_t MXB    = 20480;
    const size_t PER_B  = 2 * QB + AB + MXB;                 // 659,456

    size_t avail = (ws_size > FIXED0) ? (ws_size - FIXED0) : 0;
    int CB = (int)(avail / PER_B);
    if (CB > Bb) CB = Bb;
    if (CB < 1)  CB = 1;
    int nch = (Bb + CB - 1) / CB;
    int CBe = (Bb + nch - 1) / nch;      // balanced chunk size (<= CB)

    char*  wt2   = ws;
    float* bias2 = (float*)(ws + WT2B);
    char*  ub    = ws + WT2B + 2048;
    char*  EC    = ws + WT2B + 2048 + UBB;
    char*  embbf = ws + FIXED0;           // overlay: used only for ec_gemm
    char*  qb    = ws + FIXED0;           // overlay after ec_gemm completes
    char*  qpb   = qb  + (size_t)CB * QB;
    char*  ab    = qpb + (size_t)CB * QB;
    float* rowP  = (float*)(ab + (size_t)CB * AB);
    float* colM  = rowP + (size_t)CB * 256;
    float* scr   = colM + (size_t)CB * 1024;

    embcvt_kernel<<<NV, 128, 0, stream>>>(emb, embbf);
    prep_wt<<<512, 256, 0, stream>>>(conv_w, conv_b, (ushort16*)wt2, bias2);
    prep_ub<<<416, 256, 0, stream>>>(U, (ushort16*)ub);
    ec_gemm<<<dim3(196, 5), 512, 0, stream>>>(embbf, wt2, EC);

    for (int b0 = 0; b0 < Bb; b0 += CBe) {
        int nb = (Bb - b0 < CBe) ? (Bb - b0) : CBe;
        int nb8 = (nb + 7) / 8;
        gather_both<<<GQB + GAB, 256, 0, stream>>>(
            question + (size_t)b0 * QLn, answer + (size_t)b0 * ALn,
            EC, bias2, qb, ab, nb);
        qp_gemm<<<nb8 * 16, 512, 0, stream>>>(qb, ub, qpb, nb);
        fused_g<<<nb8 * 32, 256, 0, stream>>>((const ushort16*)qpb, (const ushort16*)ab,
                                              rowP, colM, nb);
        pool_a<<<nb * 4, 512, 0, stream>>>((const ushort16*)qb, (const ushort16*)ab,
                                           rowP, colM, scr, nb);
        pool_b<<<nb, 256, 0, stream>>>(scr, out + b0, nb);
    }
}

// Round 10
// 559.119 us; speedup vs baseline: 1.1184x; 1.0159x over previous
//
#include <hip/hip_runtime.h>
#include <math.h>

typedef unsigned int   uint32;
typedef unsigned short ushort16;
typedef __attribute__((ext_vector_type(8))) short  short8;   // 8 bf16 (MFMA A/B frag)
typedef __attribute__((ext_vector_type(4))) float  floatx4;  // MFMA C/D frag

// Problem dims
#define Bb   512
#define QLn  128
#define ALn  512
#define En   300
#define Fn   400
#define OW   416      // packed output width: 400 real + 16 zero (832 B = 13*64)
#define EPAD 320      // e padded 300 -> 320 per shift
#define NV   50001
#define ECROWS 50176  // 196*256 padded vocab rows
#define ECSTRIDE 2560 // 1280 cols * 2B (3*416 used + 32 pad)

typedef const __attribute__((address_space(1))) unsigned int guint_t;
typedef __attribute__((address_space(3))) unsigned int luint_t;
#define GLDS16(g, l) __builtin_amdgcn_global_load_lds((guint_t*)(g), (luint_t*)(l), 16, 0, 0)

static __device__ __forceinline__ float bf_lo(uint32 u) { return __uint_as_float(u << 16); }
static __device__ __forceinline__ float bf_hi(uint32 u) { return __uint_as_float(u & 0xffff0000u); }
static __device__ __forceinline__ ushort16 f2bf(float f) {
    uint32 u = __float_as_uint(f);
    uint32 r = (u + 0x7fffu + ((u >> 16) & 1u)) >> 16;   // RNE
    return (ushort16)r;
}
static __device__ __forceinline__ uint32 pack2(float a, float b) {
    return (uint32)f2bf(a) | ((uint32)f2bf(b) << 16);
}

// ---------------------------------------------------------------------------
// embcvt: embbf[v][0..320) = bf16(emb[v][0..300)), e>=300 zero.
// ---------------------------------------------------------------------------
__global__ __launch_bounds__(128) void embcvt_kernel(
        const float* __restrict__ emb, char* __restrict__ embbf)
{
    const int r = blockIdx.x, j = threadIdx.x;
    const float* er = emb + (size_t)r * En;
    uint32* orow = (uint32*)(embbf + (size_t)r * 640);
    for (int d = j; d < 160; d += 128) {
        uint32 v = 0;
        if (d < 150) {
            float2 f2v = *(const float2*)(er + 2 * d);
            v = pack2(f2v.x, f2v.y);
        }
        orow[d] = v;
    }
}

// ---------------------------------------------------------------------------
// prep_wt: Wt2[f][p] = W[f][e*3+kk] (p = kk*320+e), bf16, zero pad; bias2.
// Rows f in [400,512) are fully zero (used as zero-rows by ec_gemm pad).
// ---------------------------------------------------------------------------
__global__ __launch_bounds__(256) void prep_wt(
        const float* __restrict__ W, const float* __restrict__ cb,
        ushort16* __restrict__ Wt2, float* __restrict__ bias2)
{
    const int f = blockIdx.x, t = threadIdx.x;
    for (int p2 = t; p2 < 480; p2 += 256) {
        int p = 2 * p2;
        float v0 = 0.f, v1 = 0.f;
        if (f < Fn) {
            int kk = p / EPAD, e = p - kk * EPAD;
            if (e < En)     v0 = W[(size_t)f * 900 + e * 3 + kk];
            if (e + 1 < En) v1 = W[(size_t)f * 900 + (e + 1) * 3 + kk];
        }
        *(uint32*)&Wt2[(size_t)f * 960 + p] = pack2(v0, v1);
    }
    if (t == 0) bias2[f] = (f < Fn) ? cb[f] : 0.f;
}

// ---------------------------------------------------------------------------
// prep_ub: Ub[g][f] = bf16(U[f][g]), [416][416], zero pad both dims.
// ---------------------------------------------------------------------------
__global__ __launch_bounds__(256) void prep_ub(
        const float* __restrict__ U, ushort16* __restrict__ Ub)
{
    const int g = blockIdx.x, t = threadIdx.x;
    uint32* orow = (uint32*)(Ub + (size_t)g * 416);
    for (int f2 = t; f2 < 208; f2 += 256) {
        int f = 2 * f2;
        float v0 = 0.f, v1 = 0.f;
        if (g < Fn) {
            if (f < Fn)     v0 = U[(size_t)f * Fn + g];
            if (f + 1 < Fn) v1 = U[(size_t)(f + 1) * Fn + g];
        }
        orow[f2] = pack2(v0, v1);
    }
}

// ---------------------------------------------------------------------------
// ec_gemm: EC[v][kk*416+f] = sum_e embbf[v][e] * Wt2[f][kk*320+e]  (bf16)
// BYTE-EXACT round-3 structure (measured 78-79us; frozen).
// ---------------------------------------------------------------------------
__global__ __launch_bounds__(512) void ec_gemm(
        const char* __restrict__ embbf, const char* __restrict__ Wt2,
        char* __restrict__ EC)
{
    __shared__ __align__(16) char As[32768];   // 2 x 256 rows x 64B
    __shared__ __align__(16) char Bs[32768];
    const int t = threadIdx.x, lane = t & 63, w = t >> 6;
    const int v0 = blockIdx.x * 256, c0 = blockIdx.y * 256;
    const int wr = w >> 2, wc = w & 3;
    const int fm = lane & 15;
    const int cg = ((lane & 3) - ((lane >> 3) & 3)) & 3;
    const int rl = lane >> 2;
    const int chunkOff = (((lane >> 4) + (fm >> 1)) & 3) * 16;

    const char* srcA[2];
    const char* srcB[2];
#pragma unroll
    for (int i = 0; i < 2; ++i) {
        srcA[i] = embbf + (size_t)(v0 + w * 32 + i * 16 + rl) * 640 + cg * 16;
        int n = c0 + w * 32 + i * 16 + rl;
        int kk = n / 416, f = n - kk * 416;
        if (n >= 1248) { kk = 0; f = 508; }   // zero row
        srcB[i] = Wt2 + (size_t)f * 1920 + kk * 640 + cg * 16;
    }
    char* AsW = As + w * 2048;
    char* BsW = Bs + w * 2048;

    floatx4 acc[8][4];
    const floatx4 zz = {0.f, 0.f, 0.f, 0.f};
#pragma unroll
    for (int m = 0; m < 8; ++m)
#pragma unroll
        for (int n = 0; n < 4; ++n) acc[m][n] = zz;

#define ESTG(ko, buf) do {                                                    \
        const int _ko = (ko); const int _bo = (buf) * 16384;                  \
        GLDS16(srcA[0] + _ko, AsW + _bo);                                     \
        GLDS16(srcA[1] + _ko, AsW + _bo + 1024);                              \
        GLDS16(srcB[0] + _ko, BsW + _bo);                                     \
        GLDS16(srcB[1] + _ko, BsW + _bo + 1024);                              \
    } while (0)

    int cur = 0;
    ESTG(0, 0);
    __syncthreads();
    for (int ks = 0; ks < 10; ++ks) {
        const int nxt = cur ^ 1;
        if (ks < 9) ESTG((ks + 1) * 64, nxt);
        short8 af[8], bfv[4];
        const char* Ac = As + cur * 16384;
        const char* Bc = Bs + cur * 16384;
#pragma unroll
        for (int m = 0; m < 8; ++m)
            af[m] = *(const short8*)(Ac + (wr * 128 + m * 16 + fm) * 64 + chunkOff);
#pragma unroll
        for (int n = 0; n < 4; ++n)
            bfv[n] = *(const short8*)(Bc + (wc * 64 + n * 16 + fm) * 64 + chunkOff);
        __builtin_amdgcn_s_setprio(1);
#pragma unroll
        for (int m = 0; m < 8; ++m)
#pragma unroll
            for (int n = 0; n < 4; ++n)
                acc[m][n] = __builtin_amdgcn_mfma_f32_16x16x32_bf16(
                    af[m], bfv[n], acc[m][n], 0, 0, 0);
        __builtin_amdgcn_s_setprio(0);
        __syncthreads();
        cur = nxt;
    }
#undef ESTG

#pragma unroll
    for (int m = 0; m < 8; ++m) {
        const int v = v0 + wr * 128 + m * 16 + ((lane >> 4) * 4);
#pragma unroll
        for (int n = 0; n < 4; ++n) {
            const int col = c0 + wc * 64 + n * 16 + fm;
#pragma unroll
            for (int r = 0; r < 4; ++r)
                *(ushort16*)(EC + (size_t)(v + r) * ECSTRIDE + col * 2) =
                    f2bf(acc[m][n][r]);
        }
    }
}

// ---------------------------------------------------------------------------
// gather: out[b][l][f] = bf16( EC[t(l-1)][0*416+f] + EC[t(l)][1*416+f]
//                            + EC[t(l+1)][2*416+f] + bias[f] )
// One thread per 16B chunk (52/row). Third block region runs pool_b for the
// PREVIOUS chunk (reads only scr; pool_a(i) overwrites scr after gather(i)).
// ---------------------------------------------------------------------------
static __device__ __forceinline__ void gather_one(
        const int* __restrict__ toks, const char* __restrict__ EC,
        const float* __restrict__ bias2, char* __restrict__ outb,
        int id, int L)
{
    const uint32 uid = (uint32)id;
    const int c = (int)(uid % 52u);
    const int r = (int)(uid / 52u);
    const int l = r & (L - 1), b = r / L;   // L is 512 or 128 (pow2)
    const int* tr = toks + (size_t)b * L;
    const int t0 = (l > 0)     ? tr[l - 1] : 0;
    const int t1 = tr[l];
    const int t2 = (l < L - 1) ? tr[l + 1] : 0;
    const uint4 x0 = *(const uint4*)(EC + (size_t)t0 * ECSTRIDE +        c * 16);
    const uint4 x1 = *(const uint4*)(EC + (size_t)t1 * ECSTRIDE +  832 + c * 16);
    const uint4 x2 = *(const uint4*)(EC + (size_t)t2 * ECSTRIDE + 1664 + c * 16);
    const float4 b0 = *(const float4*)(bias2 + c * 8);
    const float4 b1 = *(const float4*)(bias2 + c * 8 + 4);
    uint4 o;
    o.x = pack2(bf_lo(x0.x) + bf_lo(x1.x) + bf_lo(x2.x) + b0.x,
                bf_hi(x0.x) + bf_hi(x1.x) + bf_hi(x2.x) + b0.y);
    o.y = pack2(bf_lo(x0.y) + bf_lo(x1.y) + bf_lo(x2.y) + b0.z,
                bf_hi(x0.y) + bf_hi(x1.y) + bf_hi(x2.y) + b0.w);
    o.z = pack2(bf_lo(x0.z) + bf_lo(x1.z) + bf_lo(x2.z) + b1.x,
                bf_hi(x0.z) + bf_hi(x1.z) + bf_hi(x2.z) + b1.y);
    o.w = pack2(bf_lo(x0.w) + bf_lo(x1.w) + bf_lo(x2.w) + b1.z,
                bf_hi(x0.w) + bf_hi(x1.w) + bf_hi(x2.w) + b1.w);
    *(uint4*)(outb + (size_t)r * 832 + c * 16) = o;
}

static __device__ __forceinline__ float red_sum_256(float v, volatile float* red) {
    int t = threadIdx.x;
    red[t] = v; __syncthreads();
    for (int s = 128; s > 0; s >>= 1) {
        if (t < s) red[t] = red[t] + red[t + s];
        __syncthreads();
    }
    float r = red[0]; __syncthreads();
    return r;
}

static __device__ __forceinline__ void pool_b_body(
        const float* __restrict__ scratch, float* __restrict__ out,
        int b, volatile float* red)
{
    const int t = threadIdx.x;
    float dd = 0.f, qq = 0.f, aam = 0.f;
    if (t < 208) {
        float q0 = 0.f, q1 = 0.f, a0 = 0.f, a1 = 0.f;
#pragma unroll
        for (int qtr = 0; qtr < 4; ++qtr) {
            const float* sc = scratch + ((size_t)b * 4 + qtr) * 832;
            q0 += sc[t]; q1 += sc[208 + t];
            a0 += sc[416 + t]; a1 += sc[624 + t];
        }
        dd  = q0 * a0 + q1 * a1;
        qq  = q0 * q0 + q1 * q1;
        aam = a0 * a0 + a1 * a1;
    }
    dd  = red_sum_256(dd, red);
    qq  = red_sum_256(qq, red);
    aam = red_sum_256(aam, red);
    if (t == 0) {
        float nq = fmaxf(sqrtf(qq), 1e-8f);
        float na = fmaxf(sqrtf(aam), 1e-8f);
        out[b] = dd / (nq * na);
    }
}

#define GQB 1024
#define GAB 4096
__global__ __launch_bounds__(256) void gather_both(
        const int* __restrict__ question, const int* __restrict__ answer,
        const char* __restrict__ EC, const float* __restrict__ bias2,
        char* __restrict__ qb, char* __restrict__ ab, int nb,
        const float* __restrict__ scrPrev, float* __restrict__ outPrev,
        int nbPrev)
{
    __shared__ float red[256];
    const int bx = blockIdx.x, t = threadIdx.x;
    if (bx < GQB) {
        const int total = nb * QLn * 52;
        for (int id = bx * 256 + t; id < total; id += GQB * 256)
            gather_one(question, EC, bias2, qb, id, QLn);
    } else if (bx < GQB + GAB) {
        const int total = nb * ALn * 52;
        for (int id = (bx - GQB) * 256 + t; id < total; id += GAB * 256)
            gather_one(answer, EC, bias2, ab, id, ALn);
    } else {
        const int b = bx - GQB - GAB;
        if (b < nbPrev) pool_b_body(scrPrev, outPrev, b, red);
    }
}

// ---------------------------------------------------------------------------
// qp_gemm (M-split): Qp[b] = Q[b] x Ub. 4 blocks/batch (mh x nt), 256 thr,
// 4 waves, 64-row tiles. nt0: cols 0..256 (MF4xNF4, wave=64 cols); nt1:
// cols 256..416 (MF2xNF5, 2x2 wave grid). ~412 blocks at CBe=103 (was 206
// x512thr, <256 CUs) -> 3-4 blocks/CU. 16-row-aligned staging groups keep
// the chunk-permutation swizzle invariant. XCD-affine: 4 variants share bx%8.
// ---------------------------------------------------------------------------
template<int MF, int NF, int BR>
static __device__ __forceinline__ void qp_tile64(
        const char* __restrict__ Qb, const char* __restrict__ Ub,
        char* __restrict__ ob, int col0, char* As, char* Bs)
{
    const int t = threadIdx.x, lane = t & 63, w = t >> 6;   // 4 waves
    const int NWN = (MF == 4) ? 4 : 2;
    const int wr = w / NWN, wc = w % NWN;
    const int fm = lane & 15;
    const int cg = ((lane & 3) - ((lane >> 3) & 3)) & 3;
    const int rl = lane >> 2;
    const int chunkOff = (((lane >> 4) + (fm >> 1)) & 3) * 16;
    const int BUFB = BR * 64;

    const char* srcQ = Qb + (size_t)(w * 16 + rl) * 832 + cg * 16;
    const char* srcB0;
    const char* srcB1 = 0;
    if (BR == 256) {
        srcB0 = Ub + (size_t)(col0 + w * 64 + rl) * 832 + cg * 16;
    } else {
        srcB0 = Ub + (size_t)(col0 + w * 32 + rl) * 832 + cg * 16;
        srcB1 = Ub + (size_t)(col0 + 128 + w * 16 + rl) * 832 + cg * 16;
    }

    floatx4 acc[MF][NF];
    const floatx4 zz = {0.f, 0.f, 0.f, 0.f};
#pragma unroll
    for (int m = 0; m < MF; ++m)
#pragma unroll
        for (int n = 0; n < NF; ++n) acc[m][n] = zz;

#define QSTG(ko, buf) do {                                                    \
        const int _ko = (ko);                                                 \
        GLDS16(srcQ + _ko, As + (buf) * 4096 + w * 1024);                     \
        if (BR == 256) {                                                      \
            GLDS16(srcB0 + _ko,         Bs + (buf) * BUFB + w * 4096);        \
            GLDS16(srcB0 + 13312 + _ko, Bs + (buf) * BUFB + w * 4096 + 1024); \
            GLDS16(srcB0 + 26624 + _ko, Bs + (buf) * BUFB + w * 4096 + 2048); \
            GLDS16(srcB0 + 39936 + _ko, Bs + (buf) * BUFB + w * 4096 + 3072); \
        } else {                                                              \
            GLDS16(srcB0 + _ko,         Bs + (buf) * BUFB + w * 2048);        \
            GLDS16(srcB0 + 13312 + _ko, Bs + (buf) * BUFB + w * 2048 + 1024); \
            if (w < 2) GLDS16(srcB1 + _ko, Bs + (buf) * BUFB + 8192 + w * 1024); \
        }                                                                     \
    } while (0)

    int cur = 0;
    QSTG(0, 0);
    __syncthreads();
    for (int ks = 0; ks < 13; ++ks) {
        const int nxt = cur ^ 1;
        if (ks < 12) QSTG((ks + 1) * 64, nxt);
        short8 af[MF], bfv[NF];
        const char* Ac = As + cur * 4096;
        const char* Bc = Bs + cur * BUFB;
#pragma unroll
        for (int m = 0; m < MF; ++m)
            af[m] = *(const short8*)(Ac + (wr * (MF * 16) + m * 16 + fm) * 64 + chunkOff);
#pragma unroll
        for (int n = 0; n < NF; ++n)
            bfv[n] = *(const short8*)(Bc + (wc * (NF * 16) + n * 16 + fm) * 64 + chunkOff);
        __builtin_amdgcn_s_setprio(1);
#pragma unroll
        for (int m = 0; m < MF; ++m)
#pragma unroll
            for (int n = 0; n < NF; ++n)
                acc[m][n] = __builtin_amdgcn_mfma_f32_16x16x32_bf16(
                    af[m], bfv[n], acc[m][n], 0, 0, 0);
        __builtin_amdgcn_s_setprio(0);
        __syncthreads();
        cur = nxt;
    }
#undef QSTG

#pragma unroll
    for (int m = 0; m < MF; ++m) {
        const int row = wr * (MF * 16) + m * 16 + ((lane >> 4) * 4);
#pragma unroll
        for (int n = 0; n < NF; ++n) {
            const int col = col0 + wc * (NF * 16) + n * 16 + fm;
#pragma unroll
            for (int r = 0; r < 4; ++r)
                *(ushort16*)(ob + (size_t)(row + r) * 832 + col * 2) =
                    f2bf(acc[m][n][r]);
        }
    }
}

__global__ __launch_bounds__(256) void qp_gemm(
        const char* __restrict__ qb, const char* __restrict__ Ub,
        char* __restrict__ qpb, int nb)
{
    __shared__ __align__(16) char As[8192];    // 2 x 64 rows x 64B
    __shared__ __align__(16) char Bs[32768];   // 2 x <=256 rows x 64B
    const int bx = blockIdx.x;
    const int xcd = bx & 7, rest = bx >> 3;
    const int nt = rest & 1, mh = (rest >> 1) & 1, b = (rest >> 2) * 8 + xcd;
    if (b >= nb) return;
    const char* Qb = qb + (size_t)b * 106496 + (size_t)mh * 64 * 832;
    char* ob = qpb + (size_t)b * 106496 + (size_t)mh * 64 * 832;
    if (nt == 0)
        qp_tile64<4, 4, 256>(Qb, Ub, ob, 0, As, Bs);
    else
        qp_tile64<2, 5, 160>(Qb, Ub, ob, 256, As, Bs);
}

// ---------------------------------------------------------------------------
// fused_g (M-split): frozen r9 form (measured win).
// ---------------------------------------------------------------------------
__global__ __launch_bounds__(256) void fused_g(
        const ushort16* __restrict__ Qp,   // [nb][128][416]
        const ushort16* __restrict__ Av,   // [nb][512][416]
        float* __restrict__ rowPart,       // [nb][2][128]
        float* __restrict__ colMg,         // [nb][2][512]
        int nb)
{
    __shared__ __align__(16) char Qs[8192];     // 2 x 64 x 64B
    __shared__ __align__(16) char Asl[32768];   // 2 x 256 x 64B
    __shared__ float rowM4[64][4];

    const int t = threadIdx.x, lane = t & 63, w = t >> 6;   // w = wave col 0..3
    const int bx = blockIdx.x;
    const int xcd = bx & 7, rest = bx >> 3;
    const int c = rest & 1, mh = (rest >> 1) & 1, b = (rest >> 2) * 8 + xcd;
    if (b >= nb) return;
    const int fm = lane & 15;
    const int cg = ((lane & 3) - ((lane >> 3) & 3)) & 3;
    const int rl = lane >> 2;
    const int chunkOff = (((lane >> 4) + (fm >> 1)) & 3) * 16;

    const char* Qpb = (const char*)Qp + (size_t)b * 106496 + (size_t)mh * 64 * 832;
    const char* Ab  = (const char*)Av + (size_t)b * 425984 + (size_t)c * 212992;
    const char* srcQ  = Qpb + (size_t)(w * 16 + rl) * 832 + cg * 16;
    const char* srcA0 = Ab  + (size_t)(w * 64 + rl) * 832 + cg * 16;

    floatx4 acc[4][4];
    const floatx4 zz = {0.f, 0.f, 0.f, 0.f};
#pragma unroll
    for (int m = 0; m < 4; ++m)
#pragma unroll
        for (int n = 0; n < 4; ++n) acc[m][n] = zz;

#define FSTG(ko, buf) do {                                                    \
        const int _ko = (ko);                                                 \
        GLDS16(srcQ + _ko,          Qs  + (buf) * 4096  + w * 1024);          \
        GLDS16(srcA0 + _ko,         Asl + (buf) * 16384 + w * 4096);          \
        GLDS16(srcA0 + 13312 + _ko, Asl + (buf) * 16384 + w * 4096 + 1024);   \
        GLDS16(srcA0 + 26624 + _ko, Asl + (buf) * 16384 + w * 4096 + 2048);   \
        GLDS16(srcA0 + 39936 + _ko, Asl + (buf) * 16384 + w * 4096 + 3072);   \
    } while (0)

    int cur = 0;
    FSTG(0, 0);
    __syncthreads();

    for (int ks = 0; ks < 13; ++ks) {
        const int nxt = cur ^ 1;
        if (ks < 12) FSTG((ks + 1) * 64, nxt);

        short8 qa[4], aa_[4];
        const char* Qc = Qs + cur * 4096;
        const char* Ac = Asl + cur * 16384;
#pragma unroll
        for (int m = 0; m < 4; ++m)
            qa[m] = *(const short8*)(Qc + (m * 16 + fm) * 64 + chunkOff);
#pragma unroll
        for (int n = 0; n < 4; ++n)
            aa_[n] = *(const short8*)(Ac + (w * 64 + n * 16 + fm) * 64 + chunkOff);
        __builtin_amdgcn_s_setprio(1);
#pragma unroll
        for (int m = 0; m < 4; ++m)
#pragma unroll
            for (int n = 0; n < 4; ++n)
                acc[m][n] = __builtin_amdgcn_mfma_f32_16x16x32_bf16(
                    qa[m], aa_[n], acc[m][n], 0, 0, 0);
        __builtin_amdgcn_s_setprio(0);
        __syncthreads();
        cur = nxt;
    }
#undef FSTG

    // rowMax partial (max over this wave's 64 A-cols) -> rowM4[row][w]
#pragma unroll
    for (int m = 0; m < 4; ++m)
#pragma unroll
        for (int r = 0; r < 4; ++r) {
            float v = fmaxf(fmaxf(acc[m][0][r], acc[m][1][r]),
                            fmaxf(acc[m][2][r], acc[m][3][r]));
            v = fmaxf(v, __shfl_xor(v, 1));
            v = fmaxf(v, __shfl_xor(v, 2));
            v = fmaxf(v, __shfl_xor(v, 4));
            v = fmaxf(v, __shfl_xor(v, 8));
            if (fm == 0) rowM4[m * 16 + (lane >> 4) * 4 + r][w] = v;
        }
    // colMax (partial over this mh-half): wave owns cols c*256+w*64+n*16+fm
#pragma unroll
    for (int n = 0; n < 4; ++n) {
        float v = -1e30f;
#pragma unroll
        for (int m = 0; m < 4; ++m)
#pragma unroll
            for (int r = 0; r < 4; ++r) v = fmaxf(v, acc[m][n][r]);
        v = fmaxf(v, __shfl_xor(v, 16));
        v = fmaxf(v, __shfl_xor(v, 32));
        if (lane < 16)
            colMg[((size_t)b * 2 + mh) * 512 + c * 256 + w * 64 + n * 16 + lane] = v;
    }
    __syncthreads();
    if (t < 64)
        rowPart[((size_t)b * 2 + c) * 128 + mh * 64 + t] =
            fmaxf(fmaxf(rowM4[t][0], rowM4[t][1]),
                  fmaxf(rowM4[t][2], rowM4[t][3]));
}

// ---------------------------------------------------------------------------
// pool_a: frozen r9 form (measured win).
// ---------------------------------------------------------------------------
static __device__ __forceinline__ float red_max_512(float v, volatile float* red) {
    int t = threadIdx.x;
    red[t] = v; __syncthreads();
    for (int s = 256; s > 0; s >>= 1) {
        if (t < s) red[t] = fmaxf(red[t], red[t + s]);
        __syncthreads();
    }
    float r = red[0]; __syncthreads();
    return r;
}
static __device__ __forceinline__ float red_sum_512(float v, volatile float* red) {
    int t = threadIdx.x;
    red[t] = v; __syncthreads();
    for (int s = 256; s > 0; s >>= 1) {
        if (t < s) red[t] = red[t] + red[t + s];
        __syncthreads();
    }
    float r = red[0]; __syncthreads();
    return r;
}

__global__ __launch_bounds__(512) void pool_a(
        const ushort16* __restrict__ Qv,   // [nb][128][416]
        const ushort16* __restrict__ Av,   // [nb][512][416]
        const float* __restrict__ rowPart, // [nb][2][128]
        const float* __restrict__ colMg,   // [nb][2][512]
        float* __restrict__ scratch,       // [nb][4][4][208]
        int nb)
{
    __shared__ float colv[ALn];
    __shared__ float roq[QLn];
    __shared__ float red[512];
    __shared__ float part[2][4][208];
    const int t = threadIdx.x, bx = blockIdx.x;
    const int qtr = bx & 3, b = bx >> 2;

    float v = -1e30f;
    if (t < QLn) {
        const float* rp = rowPart + (size_t)b * 256;
        v = tanhf(fmaxf(rp[t], rp[128 + t]));
    }
    float vmax = red_max_512(v, red);
    float ex = (t < QLn) ? __expf(v - vmax) : 0.f;
    float ssum = red_sum_512(ex, red);
    if (t < QLn) roq[t] = ex / ssum;

    const float* cm = colMg + (size_t)b * 1024;
    float cv = tanhf(fmaxf(cm[t], cm[512 + t]));
    float cmax = red_max_512(cv, red);
    float e0 = __expf(cv - cmax);
    float csum = red_sum_512(e0, red);
    colv[t] = e0 / csum;
    __syncthreads();

    if (t < 416) {
        const int half = t / 208, c = t - half * 208;
        float rq0 = 0.f, rq1 = 0.f, ra0 = 0.f, ra1 = 0.f;
        const uint32* Qb32 = (const uint32*)((const char*)Qv + (size_t)b * 106496);
        const int q0r = qtr * 32 + half * 16;
#pragma unroll 4
        for (int q = q0r; q < q0r + 16; ++q) {
            float wv = roq[q];
            uint32 u = Qb32[q * 208 + c];
            rq0 = fmaf(bf_lo(u), wv, rq0);
            rq1 = fmaf(bf_hi(u), wv, rq1);
        }
        const uint32* Ab32 = (const uint32*)((const char*)Av + (size_t)b * 425984);
        const int a0r = qtr * 128 + half * 64;
#pragma unroll 4
        for (int a = a0r; a < a0r + 64; ++a) {
            float wv = colv[a];
            uint32 u = Ab32[a * 208 + c];
            ra0 = fmaf(bf_lo(u), wv, ra0);
            ra1 = fmaf(bf_hi(u), wv, ra1);
        }
        part[half][0][c] = rq0; part[half][1][c] = rq1;
        part[half][2][c] = ra0; part[half][3][c] = ra1;
    }
    __syncthreads();

    if (t < 208) {
        float* sc = scratch + ((size_t)b * 4 + qtr) * 832;
        sc[t]       = part[0][0][t] + part[1][0][t];
        sc[208 + t] = part[0][1][t] + part[1][1][t];
        sc[416 + t] = part[0][2][t] + part[1][2][t];
        sc[624 + t] = part[0][3][t] + part[1][3][t];
    }
}

// pool_b standalone (used once for the final chunk).
__global__ __launch_bounds__(256) void pool_b(
        const float* __restrict__ scratch, float* __restrict__ out, int nb)
{
    __shared__ float red[256];
    pool_b_body(scratch, out, blockIdx.x, red);
}

// ---------------------------------------------------------------------------
// launch — ws: [Wt2 | bias2 | Ub | EC | overlay{embbf | per-chunk bufs}]
// per-batch aux: rowPart 1KB + colMg 4KB + scratch 13312B <= MXB 20480.
// ---------------------------------------------------------------------------
extern "C" void kernel_launch(void* const* d_in, const int* in_sizes, int n_in,
                              void* d_out, int out_size, void* d_ws, size_t ws_size,
                              hipStream_t stream)
{
    const int*   question = (const int*)d_in[0];
    const int*   answer   = (const int*)d_in[1];
    const float* emb      = (const float*)d_in[2];
    const float* conv_w   = (const float*)d_in[3];
    const float* conv_b   = (const float*)d_in[4];
    const float* U        = (const float*)d_in[5];
    float* out = (float*)d_out;
    char* ws = (char*)d_ws;

    const size_t WT2B   = (size_t)512 * 960 * 2;             // 983,040
    const size_t UBB    = (size_t)416 * 416 * 2;             // 346,112
    const size_t ECB    = (size_t)ECROWS * ECSTRIDE;         // 128,450,560
    const size_t FIXED0 = WT2B + 2048 + UBB + ECB;           // 129,781,760
    const size_t QB     = (size_t)QLn * OW * 2;              // 106,496
    const size_t AB     = (size_t)ALn * OW * 2;              // 425,984
    const size_t MXB    = 20480;
    const size_t PER_B  = 2 * QB + AB + MXB;                 // 659,456

    size_t avail = (ws_size > FIXED0) ? (ws_size - FIXED0) : 0;
    int CB = (int)(avail / PER_B);
    if (CB > Bb) CB = Bb;
    if (CB < 1)  CB = 1;
    int nch = (Bb + CB - 1) / CB;
    int CBe = (Bb + nch - 1) / nch;      // balanced chunk size (<= CB)

    char*  wt2   = ws;
    float* bias2 = (float*)(ws + WT2B);
    char*  ub    = ws + WT2B + 2048;
    char*  EC    = ws + WT2B + 2048 + UBB;
    char*  embbf = ws + FIXED0;           // overlay: used only for ec_gemm
    char*  qb    = ws + FIXED0;           // overlay after ec_gemm completes
    char*  qpb   = qb  + (size_t)CB * QB;
    char*  ab    = qpb + (size_t)CB * QB;
    float* rowP  = (float*)(ab + (size_t)CB * AB);
    float* colM  = rowP + (size_t)CB * 256;
    float* scr   = colM + (size_t)CB * 1024;

    embcvt_kernel<<<NV, 128, 0, stream>>>(emb, embbf);
    prep_wt<<<512, 256, 0, stream>>>(conv_w, conv_b, (ushort16*)wt2, bias2);
    prep_ub<<<416, 256, 0, stream>>>(U, (ushort16*)ub);
    ec_gemm<<<dim3(196, 5), 512, 0, stream>>>(embbf, wt2, EC);

    int prevNb = 0;
    float* prevOut = out;
    for (int b0 = 0; b0 < Bb; b0 += CBe) {
        int nb = (Bb - b0 < CBe) ? (Bb - b0) : CBe;
        int nb8 = (nb + 7) / 8;
        gather_both<<<GQB + GAB + prevNb, 256, 0, stream>>>(
            question + (size_t)b0 * QLn, answer + (size_t)b0 * ALn,
            EC, bias2, qb, ab, nb, scr, prevOut, prevNb);
        qp_gemm<<<nb8 * 32, 256, 0, stream>>>(qb, ub, qpb, nb);
        fused_g<<<nb8 * 32, 256, 0, stream>>>((const ushort16*)qpb, (const ushort16*)ab,
                                              rowP, colM, nb);
        pool_a<<<nb * 4, 512, 0, stream>>>((const ushort16*)qb, (const ushort16*)ab,
                                           rowP, colM, scr, nb);
        prevNb = nb;
        prevOut = out + b0;
    }
    pool_b<<<prevNb, 256, 0, stream>>>(scr, prevOut, prevNb);
}